// Round 1
// baseline (310.496 us; speedup 1.0000x reference)
//
#include <hip/hip_runtime.h>

typedef _Float16 h8 __attribute__((ext_vector_type(8)));
typedef float f32x4 __attribute__((ext_vector_type(4)));

#define NSEQ 2048
#define MTOT 4096
#define DMODEL 1024
#define HD 64

// ---------------- workspace layout (bytes) ----------------
#define OFF_HPE  (size_t)0           // 4096x1024 f16 = 8MB
#define OFF_WQ   (size_t)8388608     // 1024x1024 f16 = 2MB
#define OFF_WK   (size_t)10485760
#define OFF_WV   (size_t)12582912
#define OFF_WO   (size_t)14680064
#define OFF_Q    (size_t)16777216    // 4096x1024 f16 = 8MB
#define OFF_K    (size_t)25165824
#define OFF_VT   (size_t)33554432    // [2][1024][2048] f16 = 8MB (V transposed per head)
#define OFF_AO   (size_t)41943040    // 4096x1024 f16 = 8MB
#define OFF_PB   (size_t)50331648    // [2][2048] f32 = 16KB

// ---------------- prep kernels ----------------
__global__ void hpe_kernel(const float* __restrict__ h, _Float16* __restrict__ hpe) {
    int idx = blockIdx.x * blockDim.x + threadIdx.x;   // over [4096][512] (sin/cos pairs)
    int row = idx >> 9;
    int i2  = idx & 511;
    int n = row & (NSEQ - 1);
    const float kTerm = -9.210340371976184f / 1024.0f; // -ln(10000)/1024
    float div = expf((float)(2 * i2) * kTerm);
    float ang = (float)n * div;
    float s = sinf(ang), c = cosf(ang);
    int base = row * DMODEL + 2 * i2;
    hpe[base]     = (_Float16)(h[base] + s);
    hpe[base + 1] = (_Float16)(h[base + 1] + c);
}

__global__ void cast_kernel(const float* __restrict__ src, _Float16* __restrict__ dst) {
    int i = blockIdx.x * blockDim.x + threadIdx.x;     // n/4 threads
    float4 v = ((const float4*)src)[i];
    union { _Float16 hh[4]; uint2 u; } o;
    o.hh[0] = (_Float16)v.x; o.hh[1] = (_Float16)v.y;
    o.hh[2] = (_Float16)v.z; o.hh[3] = (_Float16)v.w;
    ((uint2*)dst)[i] = o.u;
}

__global__ void pb_kernel(const float* __restrict__ probs, const float* __restrict__ pbs,
                          float* __restrict__ pb) {
    int i = blockIdx.x * blockDim.x + threadIdx.x;     // 4096
    pb[i] = pbs[0] * logf(probs[i] + 1e-8f);
}

// ---------------- GEMM: C[M=4096][1024] = A[4096][1024] @ W[1024][1024]^T + bias ----------------
// MODE 0: fp16 out row-major; MODE 1: fp16 out transposed-per-(b,col) for V; MODE 2: f32 out.
#define BM 128
#define BN 128
#define BK 64
#define LDT 72   // padded stride (halfs); 72 ≡ 8 (mod 64) → ≤2-way LDS bank aliasing

template<int MODE>
__global__ __launch_bounds__(256) void gemm_nt(
    const _Float16* __restrict__ A, const _Float16* __restrict__ W,
    const float* __restrict__ bias, void* __restrict__ Cout)
{
    __shared__ __align__(16) _Float16 As[BM][LDT];
    __shared__ __align__(16) _Float16 Bs[BN][LDT];
    const int K = DMODEL;
    int tm = blockIdx.x * BM;
    int tn = blockIdx.y * BN;
    int t = threadIdx.x;
    int wave = t >> 6, lane = t & 63;
    int wr = (wave >> 1) * 64, wc = (wave & 1) * 64;
    int lr = lane & 15, lg = lane >> 4;

    f32x4 acc[4][4] = {};

    int srow = t >> 3, sc = (t & 7) * 8;

    for (int k0 = 0; k0 < K; k0 += BK) {
        __syncthreads();
        #pragma unroll
        for (int p = 0; p < 4; ++p) {
            int r = p * 32 + srow;
            *(h8*)&As[r][sc] = *(const h8*)&A[(size_t)(tm + r) * K + k0 + sc];
            *(h8*)&Bs[r][sc] = *(const h8*)&W[(size_t)(tn + r) * K + k0 + sc];
        }
        __syncthreads();
        #pragma unroll
        for (int kk = 0; kk < 2; ++kk) {
            h8 af[4], bf[4];
            #pragma unroll
            for (int i = 0; i < 4; ++i) {
                af[i] = *(const h8*)&As[wr + i * 16 + lr][kk * 32 + lg * 8];
                bf[i] = *(const h8*)&Bs[wc + i * 16 + lr][kk * 32 + lg * 8];
            }
            #pragma unroll
            for (int mi = 0; mi < 4; ++mi)
                #pragma unroll
                for (int ni = 0; ni < 4; ++ni)
                    acc[mi][ni] = __builtin_amdgcn_mfma_f32_16x16x32_f16(af[mi], bf[ni], acc[mi][ni], 0, 0, 0);
        }
    }

    #pragma unroll
    for (int mi = 0; mi < 4; ++mi)
        #pragma unroll
        for (int ni = 0; ni < 4; ++ni)
            #pragma unroll
            for (int j = 0; j < 4; ++j) {
                int row = tm + wr + mi * 16 + lg * 4 + j;
                int col = tn + wc + ni * 16 + lr;
                float v = acc[mi][ni][j] + bias[col];
                if (MODE == 0) {
                    ((_Float16*)Cout)[(size_t)row * DMODEL + col] = (_Float16)v;
                } else if (MODE == 1) {
                    int b = row >> 11, nn = row & 2047;
                    ((_Float16*)Cout)[((size_t)b * 1024 + col) * 2048 + nn] = (_Float16)v;
                } else {
                    ((float*)Cout)[(size_t)row * DMODEL + col] = v;
                }
            }
}

// ---------------- flash attention ----------------
// grid (16 q-tiles, 32 (b,h)); 256 threads = 4 waves; wave owns 32 q-rows; KV tile = 64 keys.
#define QT 128
#define KT 64

__global__ __launch_bounds__(256) void flash_kernel(
    const _Float16* __restrict__ Qb,   // [4096][1024]
    const _Float16* __restrict__ Kb,   // [4096][1024]
    const _Float16* __restrict__ Vt,   // [2][1024][2048]
    const float* __restrict__ pb,      // [2][2048]
    _Float16* __restrict__ AO)         // [4096][1024]
{
    __shared__ __align__(16) _Float16 Qs[QT][LDT];     // 18KB
    __shared__ __align__(16) _Float16 Ks[KT][LDT];     // 9KB
    __shared__ __align__(16) _Float16 Vs[HD][LDT];     // 9KB (V^T tile: [col][key])
    __shared__ __align__(16) _Float16 Ps[4][32][LDT];  // 18KB per-wave P staging

    int bh = blockIdx.y;
    int b = bh >> 4, h = bh & 15;
    int q0 = blockIdx.x * QT;
    int t = threadIdx.x, wave = t >> 6, lane = t & 63;
    int lr = lane & 15, lg = lane >> 4;

    const _Float16* Qhead = Qb + (size_t)b * NSEQ * DMODEL + h * HD;
    const _Float16* Khead = Kb + (size_t)b * NSEQ * DMODEL + h * HD;
    const _Float16* Vthead = Vt + ((size_t)b * 1024 + h * HD) * NSEQ;
    const float* pbb = pb + b * NSEQ;

    // stage Q tile once: 128 rows x 64 halfs
    {
        int srow = t >> 3, sc = (t & 7) * 8;
        #pragma unroll
        for (int p = 0; p < 4; ++p) {
            int r = p * 32 + srow;
            *(h8*)&Qs[r][sc] = *(const h8*)&Qhead[(size_t)(q0 + r) * DMODEL + sc];
        }
    }

    float mrun[2][4], lrun[2][4];
    f32x4 oacc[2][4] = {};
    #pragma unroll
    for (int ri = 0; ri < 2; ++ri)
        #pragma unroll
        for (int j = 0; j < 4; ++j) { mrun[ri][j] = -INFINITY; lrun[ri][j] = 0.f; }

    for (int k0 = 0; k0 < NSEQ; k0 += KT) {
        __syncthreads();
        {
            int srow = t >> 3, sc = (t & 7) * 8;
            #pragma unroll
            for (int p = 0; p < 2; ++p) {
                int r = p * 32 + srow;
                *(h8*)&Ks[r][sc] = *(const h8*)&Khead[(size_t)(k0 + r) * DMODEL + sc];
                *(h8*)&Vs[r][sc] = *(const h8*)&Vthead[(size_t)r * NSEQ + k0 + sc];
            }
        }
        __syncthreads();

        // S = (Q K^T) * 0.125 + bias
        f32x4 s[2][4] = {};
        #pragma unroll
        for (int kk = 0; kk < 2; ++kk) {
            h8 qf[2], kf[4];
            #pragma unroll
            for (int i = 0; i < 2; ++i) qf[i] = *(const h8*)&Qs[wave * 32 + i * 16 + lr][kk * 32 + lg * 8];
            #pragma unroll
            for (int i = 0; i < 4; ++i) kf[i] = *(const h8*)&Ks[i * 16 + lr][kk * 32 + lg * 8];
            #pragma unroll
            for (int ri = 0; ri < 2; ++ri)
                #pragma unroll
                for (int ci = 0; ci < 4; ++ci)
                    s[ri][ci] = __builtin_amdgcn_mfma_f32_16x16x32_f16(qf[ri], kf[ci], s[ri][ci], 0, 0, 0);
        }
        float pbv[4];
        #pragma unroll
        for (int ci = 0; ci < 4; ++ci) pbv[ci] = pbb[k0 + ci * 16 + lr];
        #pragma unroll
        for (int ri = 0; ri < 2; ++ri)
            #pragma unroll
            for (int ci = 0; ci < 4; ++ci)
                #pragma unroll
                for (int j = 0; j < 4; ++j)
                    s[ri][ci][j] = s[ri][ci][j] * 0.125f + pbv[ci];

        // online softmax (rows r = lg*4+j within each 16-block; cols = ci*16+lr)
        #pragma unroll
        for (int ri = 0; ri < 2; ++ri)
            #pragma unroll
            for (int j = 0; j < 4; ++j) {
                float sm = fmaxf(fmaxf(s[ri][0][j], s[ri][1][j]), fmaxf(s[ri][2][j], s[ri][3][j]));
                #pragma unroll
                for (int mask = 1; mask < 16; mask <<= 1) sm = fmaxf(sm, __shfl_xor(sm, mask));
                float newm = fmaxf(mrun[ri][j], sm);
                float fs = __expf(mrun[ri][j] - newm);
                float pj[4]; float rs = 0.f;
                #pragma unroll
                for (int ci = 0; ci < 4; ++ci) { pj[ci] = __expf(s[ri][ci][j] - newm); rs += pj[ci]; }
                #pragma unroll
                for (int mask = 1; mask < 16; mask <<= 1) rs += __shfl_xor(rs, mask);
                lrun[ri][j] = lrun[ri][j] * fs + rs;
                mrun[ri][j] = newm;
                #pragma unroll
                for (int ni = 0; ni < 4; ++ni) oacc[ri][ni][j] *= fs;
                #pragma unroll
                for (int ci = 0; ci < 4; ++ci)
                    Ps[wave][ri * 16 + lg * 4 + j][ci * 16 + lr] = (_Float16)pj[ci];
            }
        // make P writes visible to other lanes of this wave (wave-synchronous, no block barrier)
        asm volatile("s_waitcnt lgkmcnt(0)" ::: "memory");

        // O += P @ V
        #pragma unroll
        for (int kb = 0; kb < 2; ++kb) {
            h8 pa[2], vf[4];
            #pragma unroll
            for (int ri = 0; ri < 2; ++ri) pa[ri] = *(const h8*)&Ps[wave][ri * 16 + lr][kb * 32 + lg * 8];
            #pragma unroll
            for (int ni = 0; ni < 4; ++ni) vf[ni] = *(const h8*)&Vs[ni * 16 + lr][kb * 32 + lg * 8];
            #pragma unroll
            for (int ri = 0; ri < 2; ++ri)
                #pragma unroll
                for (int ni = 0; ni < 4; ++ni)
                    oacc[ri][ni] = __builtin_amdgcn_mfma_f32_16x16x32_f16(pa[ri], vf[ni], oacc[ri][ni], 0, 0, 0);
        }
    }

    // write out: AO[b*2048 + q0 + wave*32 + row][h*64 + col]
    #pragma unroll
    for (int ri = 0; ri < 2; ++ri)
        #pragma unroll
        for (int ni = 0; ni < 4; ++ni)
            #pragma unroll
            for (int j = 0; j < 4; ++j) {
                int row = q0 + wave * 32 + ri * 16 + lg * 4 + j;
                int col = h * HD + ni * 16 + lr;
                float v = oacc[ri][ni][j] / lrun[ri][j];
                AO[((size_t)b * NSEQ + row) * DMODEL + col] = (_Float16)v;
            }
}

// ---------------- launcher ----------------
extern "C" void kernel_launch(void* const* d_in, const int* in_sizes, int n_in,
                              void* d_out, int out_size, void* d_ws, size_t ws_size,
                              hipStream_t stream) {
    const float* h    = (const float*)d_in[0];
    const float* prob = (const float*)d_in[1];
    const float* Wq   = (const float*)d_in[2];
    const float* bq   = (const float*)d_in[3];
    const float* Wk   = (const float*)d_in[4];
    const float* bk   = (const float*)d_in[5];
    const float* Wv   = (const float*)d_in[6];
    const float* bv   = (const float*)d_in[7];
    const float* Wo   = (const float*)d_in[8];
    const float* bo   = (const float*)d_in[9];
    const float* pbs  = (const float*)d_in[10];

    char* ws = (char*)d_ws;
    _Float16* hpe  = (_Float16*)(ws + OFF_HPE);
    _Float16* wq16 = (_Float16*)(ws + OFF_WQ);
    _Float16* wk16 = (_Float16*)(ws + OFF_WK);
    _Float16* wv16 = (_Float16*)(ws + OFF_WV);
    _Float16* wo16 = (_Float16*)(ws + OFF_WO);
    _Float16* qb   = (_Float16*)(ws + OFF_Q);
    _Float16* kb16 = (_Float16*)(ws + OFF_K);
    _Float16* vt   = (_Float16*)(ws + OFF_VT);
    _Float16* ao   = (_Float16*)(ws + OFF_AO);
    float*    pbuf = (float*)(ws + OFF_PB);

    hpe_kernel<<<dim3(8192), dim3(256), 0, stream>>>(h, hpe);
    cast_kernel<<<dim3(1024), dim3(256), 0, stream>>>(Wq, wq16);
    cast_kernel<<<dim3(1024), dim3(256), 0, stream>>>(Wk, wk16);
    cast_kernel<<<dim3(1024), dim3(256), 0, stream>>>(Wv, wv16);
    cast_kernel<<<dim3(1024), dim3(256), 0, stream>>>(Wo, wo16);
    pb_kernel<<<dim3(16), dim3(256), 0, stream>>>(prob, pbs, pbuf);

    gemm_nt<0><<<dim3(32, 8), dim3(256), 0, stream>>>(hpe, wq16, bq, qb);
    gemm_nt<0><<<dim3(32, 8), dim3(256), 0, stream>>>(hpe, wk16, bk, kb16);
    gemm_nt<1><<<dim3(32, 8), dim3(256), 0, stream>>>(hpe, wv16, bv, vt);

    flash_kernel<<<dim3(16, 32), dim3(256), 0, stream>>>(qb, kb16, vt, pbuf, ao);

    gemm_nt<2><<<dim3(32, 8), dim3(256), 0, stream>>>(ao, wo16, bo, d_out);
}

// Round 2
// 264.860 us; speedup vs baseline: 1.1723x; 1.1723x over previous
//
#include <hip/hip_runtime.h>

typedef _Float16 h8 __attribute__((ext_vector_type(8)));
typedef float f32x4 __attribute__((ext_vector_type(4)));

#define NSEQ 2048
#define DMODEL 1024
#define HD 64
#define C2 0.1803368801111244f   // 0.125 * log2(e)

// ---------------- workspace layout (bytes) ----------------
#define OFF_HPE  (size_t)0           // 4096x1024 f16 = 8MB
#define OFF_WQ   (size_t)8388608     // 1024x1024 f16 = 2MB
#define OFF_WK   (size_t)10485760
#define OFF_WV   (size_t)12582912
#define OFF_WO   (size_t)14680064
#define OFF_Q    (size_t)16777216    // 4096x1024 f16 = 8MB
#define OFF_K    (size_t)25165824
#define OFF_VT   (size_t)33554432    // [2][1024][2048] f16 = 8MB (V^T per head)
#define OFF_AO   (size_t)41943040    // 4096x1024 f16 = 8MB
#define OFF_PB   (size_t)50331648    // [2][2048] f32 (log2-domain bias)

#define GLL(g, l) __builtin_amdgcn_global_load_lds( \
    (const __attribute__((address_space(1))) unsigned int*)(const void*)(g), \
    (__attribute__((address_space(3))) unsigned int*)(l), 16, 0, 0)

// ---------------- prep kernels ----------------
__global__ void hpe_kernel(const float* __restrict__ h, _Float16* __restrict__ hpe) {
    int idx = blockIdx.x * blockDim.x + threadIdx.x;   // over [4096][512] sin/cos pairs
    int row = idx >> 9;
    int i2  = idx & 511;
    int n = row & (NSEQ - 1);
    const float kTerm = -9.210340371976184f / 1024.0f; // -ln(10000)/1024
    float div = expf((float)(2 * i2) * kTerm);
    float ang = (float)n * div;
    float s = sinf(ang), c = cosf(ang);
    int base = row * DMODEL + 2 * i2;
    hpe[base]     = (_Float16)(h[base] + s);
    hpe[base + 1] = (_Float16)(h[base + 1] + c);
}

__global__ void cast_kernel(const float* __restrict__ src, _Float16* __restrict__ dst) {
    int i = blockIdx.x * blockDim.x + threadIdx.x;
    float4 v = ((const float4*)src)[i];
    union { _Float16 hh[4]; uint2 u; } o;
    o.hh[0] = (_Float16)v.x; o.hh[1] = (_Float16)v.y;
    o.hh[2] = (_Float16)v.z; o.hh[3] = (_Float16)v.w;
    ((uint2*)dst)[i] = o.u;
}

// log2-domain key bias: pb = pbs * log2(probs + 1e-8)
__global__ void pb_kernel(const float* __restrict__ probs, const float* __restrict__ pbs,
                          float* __restrict__ pb) {
    int i = blockIdx.x * blockDim.x + threadIdx.x;     // 4096
    pb[i] = pbs[0] * log2f(probs[i] + 1e-8f);
}

// ---------------- GEMM: C[4096][1024] = A[4096][1024] @ W[1024][1024]^T + bias ----------------
// m97 structure: 128x64 tile, BK=64, global_load_lds(16B) staging, linear LDS.
// MODE 0: f16 row-major; MODE 1: f16 V^T per (b,col); MODE 2: f32.
#define GBM 128
#define GBN 64

template<int MODE>
__global__ __launch_bounds__(256) void gemm_nt(
    const _Float16* __restrict__ A, const _Float16* __restrict__ W,
    const float* __restrict__ bias, void* __restrict__ Cout)
{
    __shared__ __align__(16) _Float16 As[GBM][64];   // 16KB
    __shared__ __align__(16) _Float16 Bs[GBN][64];   // 8KB
    int tm = blockIdx.x * GBM;
    int tn = blockIdx.y * GBN;
    int t = threadIdx.x;
    int wave = t >> 6, lane = t & 63;
    int wr = (wave >> 1) * 64, wc = (wave & 1) * 32;
    int lr = lane & 15, lg = lane >> 4;

    f32x4 acc[4][2] = {};

    // staging source: lane covers row (lane>>3), 16B chunk (lane&7) of each 8-row block
    int grow = lane >> 3;
    int gcol = (lane & 7) * 8;
    const _Float16* Aptr = A + (size_t)(tm + wave * 8 + grow) * DMODEL + gcol;
    const _Float16* Wptr = W + (size_t)(tn + wave * 8 + grow) * DMODEL + gcol;

    for (int k0 = 0; k0 < DMODEL; k0 += 64) {
        __syncthreads();
        #pragma unroll
        for (int i = 0; i < 4; ++i)
            GLL(Aptr + (size_t)i * 32 * DMODEL + k0, &As[i * 32 + wave * 8][0]);
        #pragma unroll
        for (int i = 0; i < 2; ++i)
            GLL(Wptr + (size_t)i * 32 * DMODEL + k0, &Bs[i * 32 + wave * 8][0]);
        __syncthreads();
        #pragma unroll
        for (int kk = 0; kk < 2; ++kk) {
            h8 af[4], bf[2];
            #pragma unroll
            for (int mi = 0; mi < 4; ++mi) af[mi] = *(const h8*)&As[wr + mi * 16 + lr][kk * 32 + lg * 8];
            #pragma unroll
            for (int ni = 0; ni < 2; ++ni) bf[ni] = *(const h8*)&Bs[wc + ni * 16 + lr][kk * 32 + lg * 8];
            #pragma unroll
            for (int mi = 0; mi < 4; ++mi)
                #pragma unroll
                for (int ni = 0; ni < 2; ++ni)
                    acc[mi][ni] = __builtin_amdgcn_mfma_f32_16x16x32_f16(af[mi], bf[ni], acc[mi][ni], 0, 0, 0);
        }
    }

    #pragma unroll
    for (int mi = 0; mi < 4; ++mi)
        #pragma unroll
        for (int ni = 0; ni < 2; ++ni)
            #pragma unroll
            for (int j = 0; j < 4; ++j) {
                int row = tm + wr + mi * 16 + lg * 4 + j;
                int col = tn + wc + ni * 16 + lr;
                float v = acc[mi][ni][j] + bias[col];
                if (MODE == 0) {
                    ((_Float16*)Cout)[(size_t)row * DMODEL + col] = (_Float16)v;
                } else if (MODE == 1) {
                    int b = row >> 11, nn = row & 2047;
                    ((_Float16*)Cout)[((size_t)b * 1024 + col) * 2048 + nn] = (_Float16)v;
                } else {
                    ((float*)Cout)[(size_t)row * DMODEL + col] = v;
                }
            }
}

// ---------------- flash attention v2 (swapped QK^T, lane-local softmax) ----------------
// grid (32 q-tiles of 64, 32 bh); 256 threads = 4 waves; wave owns 16 q-rows; KV tile 64.
#define QT 64
#define KT 64

__global__ __launch_bounds__(256, 4) void flash_kernel(
    const _Float16* __restrict__ Qb,   // [4096][1024]
    const _Float16* __restrict__ Kb,   // [4096][1024]
    const _Float16* __restrict__ Vt,   // [2][1024][2048]
    const float* __restrict__ pb,      // [2][2048] log2-domain
    _Float16* __restrict__ AO)         // [4096][1024]
{
    __shared__ __align__(16) _Float16 Ks[KT][72];      // 9KB
    __shared__ __align__(16) _Float16 Vs[HD][72];      // 9KB  (V^T tile: [d][k])
    __shared__ __align__(16) _Float16 Ps[4][16][72];   // 9KB  per-wave P
    int bh = blockIdx.y;
    int b = bh >> 4, h = bh & 15;
    int q0 = blockIdx.x * QT;
    int t = threadIdx.x, wave = t >> 6, lane = t & 63;
    int lr = lane & 15, lg = lane >> 4;

    const _Float16* Khead  = Kb + (size_t)b * NSEQ * DMODEL + h * HD;
    const _Float16* Vthead = Vt + ((size_t)b * 1024 + h * HD) * NSEQ;
    const float* pbb = pb + b * NSEQ;

    // Q fragment in registers (B-operand): lane holds Q row q = q0 + wave*16 + lr
    const _Float16* Qrow = Qb + ((size_t)b * NSEQ + q0 + wave * 16 + lr) * DMODEL + h * HD;
    h8 qf0 = *(const h8*)&Qrow[lg * 8];
    h8 qf1 = *(const h8*)&Qrow[32 + lg * 8];

    float mrun = -INFINITY, lrun = 0.f;   // for q = lr-row (dup across lg)
    f32x4 oacc[4] = {};                   // O[q = lg*4+j][d = ni*16+lr]

    int srow = t >> 2, sc = (t & 3) * 16;

    for (int k0 = 0; k0 < NSEQ; k0 += KT) {
        // per-key bias (L1-resident, issue early)
        f32x4 pbv[4];
        #pragma unroll
        for (int ci = 0; ci < 4; ++ci)
            pbv[ci] = *(const f32x4*)&pbb[k0 + ci * 16 + lg * 4];

        __syncthreads();
        *(h8*)&Ks[srow][sc]     = *(const h8*)&Khead[(size_t)(k0 + srow) * DMODEL + sc];
        *(h8*)&Ks[srow][sc + 8] = *(const h8*)&Khead[(size_t)(k0 + srow) * DMODEL + sc + 8];
        *(h8*)&Vs[srow][sc]     = *(const h8*)&Vthead[(size_t)srow * NSEQ + k0 + sc];
        *(h8*)&Vs[srow][sc + 8] = *(const h8*)&Vthead[(size_t)srow * NSEQ + k0 + sc + 8];
        __syncthreads();

        // S^T = K Q^T : lane holds S[q=lr][k = ci*16 + lg*4 + j]
        f32x4 s[4] = {};
        #pragma unroll
        for (int ci = 0; ci < 4; ++ci) {
            h8 kf = *(const h8*)&Ks[ci * 16 + lr][lg * 8];
            s[ci] = __builtin_amdgcn_mfma_f32_16x16x32_f16(kf, qf0, s[ci], 0, 0, 0);
        }
        #pragma unroll
        for (int ci = 0; ci < 4; ++ci) {
            h8 kf = *(const h8*)&Ks[ci * 16 + lr][32 + lg * 8];
            s[ci] = __builtin_amdgcn_mfma_f32_16x16x32_f16(kf, qf1, s[ci], 0, 0, 0);
        }

        // log2-domain scores; lane-local row max
        float p[4][4];
        float sm = -INFINITY;
        #pragma unroll
        for (int ci = 0; ci < 4; ++ci)
            #pragma unroll
            for (int j = 0; j < 4; ++j) {
                float vv = fmaf(s[ci][j], C2, pbv[ci][j]);
                p[ci][j] = vv;
                sm = fmaxf(sm, vv);
            }
        sm = fmaxf(sm, __shfl_xor(sm, 16));
        sm = fmaxf(sm, __shfl_xor(sm, 32));
        float newm = fmaxf(mrun, sm);
        float fs = __builtin_amdgcn_exp2f(mrun - newm);
        float rs = 0.f;
        #pragma unroll
        for (int ci = 0; ci < 4; ++ci)
            #pragma unroll
            for (int j = 0; j < 4; ++j) {
                float e = __builtin_amdgcn_exp2f(p[ci][j] - newm);
                p[ci][j] = e;
                rs += e;
            }
        rs += __shfl_xor(rs, 16);
        rs += __shfl_xor(rs, 32);
        lrun = lrun * fs + rs;
        mrun = newm;

        // P^T -> LDS: lane writes P[q=lr][k=ci*16+lg*4 .. +4] as one b64
        #pragma unroll
        for (int ci = 0; ci < 4; ++ci) {
            union { _Float16 hh[4]; uint2 u; } pk;
            #pragma unroll
            for (int j = 0; j < 4; ++j) pk.hh[j] = (_Float16)p[ci][j];
            *(uint2*)&Ps[wave][lr][ci * 16 + lg * 4] = pk.u;
        }
        asm volatile("s_waitcnt lgkmcnt(0)" ::: "memory");
        __builtin_amdgcn_sched_barrier(0);

        // rescale O by fs of its q-row (fs uniform across lg for given lr)
        #pragma unroll
        for (int j = 0; j < 4; ++j) {
            float fsj = __shfl(fs, (lane & 48) | (lg * 4 + j), 64);
            #pragma unroll
            for (int ni = 0; ni < 4; ++ni) oacc[ni][j] *= fsj;
        }

        // O += P @ V
        #pragma unroll
        for (int kb = 0; kb < 2; ++kb) {
            h8 pa = *(const h8*)&Ps[wave][lr][kb * 32 + lg * 8];
            #pragma unroll
            for (int ni = 0; ni < 4; ++ni) {
                h8 vf = *(const h8*)&Vs[ni * 16 + lr][kb * 32 + lg * 8];
                oacc[ni] = __builtin_amdgcn_mfma_f32_16x16x32_f16(pa, vf, oacc[ni], 0, 0, 0);
            }
        }
    }

    // epilogue: divide by lrun of the row, write out
    #pragma unroll
    for (int j = 0; j < 4; ++j) {
        float lj = __shfl(lrun, (lane & 48) | (lg * 4 + j), 64);
        float inv = 1.0f / lj;
        int row = q0 + wave * 16 + lg * 4 + j;
        #pragma unroll
        for (int ni = 0; ni < 4; ++ni)
            AO[((size_t)b * NSEQ + row) * DMODEL + h * HD + ni * 16 + lr] = (_Float16)(oacc[ni][j] * inv);
    }
}

// ---------------- launcher ----------------
extern "C" void kernel_launch(void* const* d_in, const int* in_sizes, int n_in,
                              void* d_out, int out_size, void* d_ws, size_t ws_size,
                              hipStream_t stream) {
    const float* h    = (const float*)d_in[0];
    const float* prob = (const float*)d_in[1];
    const float* Wq   = (const float*)d_in[2];
    const float* bq   = (const float*)d_in[3];
    const float* Wk   = (const float*)d_in[4];
    const float* bk   = (const float*)d_in[5];
    const float* Wv   = (const float*)d_in[6];
    const float* bv   = (const float*)d_in[7];
    const float* Wo   = (const float*)d_in[8];
    const float* bo   = (const float*)d_in[9];
    const float* pbs  = (const float*)d_in[10];

    char* ws = (char*)d_ws;
    _Float16* hpe  = (_Float16*)(ws + OFF_HPE);
    _Float16* wq16 = (_Float16*)(ws + OFF_WQ);
    _Float16* wk16 = (_Float16*)(ws + OFF_WK);
    _Float16* wv16 = (_Float16*)(ws + OFF_WV);
    _Float16* wo16 = (_Float16*)(ws + OFF_WO);
    _Float16* qb   = (_Float16*)(ws + OFF_Q);
    _Float16* kb16 = (_Float16*)(ws + OFF_K);
    _Float16* vt   = (_Float16*)(ws + OFF_VT);
    _Float16* ao   = (_Float16*)(ws + OFF_AO);
    float*    pbuf = (float*)(ws + OFF_PB);

    hpe_kernel<<<dim3(8192), dim3(256), 0, stream>>>(h, hpe);
    cast_kernel<<<dim3(1024), dim3(256), 0, stream>>>(Wq, wq16);
    cast_kernel<<<dim3(1024), dim3(256), 0, stream>>>(Wk, wk16);
    cast_kernel<<<dim3(1024), dim3(256), 0, stream>>>(Wv, wv16);
    cast_kernel<<<dim3(1024), dim3(256), 0, stream>>>(Wo, wo16);
    pb_kernel<<<dim3(16), dim3(256), 0, stream>>>(prob, pbs, pbuf);

    gemm_nt<0><<<dim3(32, 16), dim3(256), 0, stream>>>(hpe, wq16, bq, qb);
    gemm_nt<0><<<dim3(32, 16), dim3(256), 0, stream>>>(hpe, wk16, bk, kb16);
    gemm_nt<1><<<dim3(32, 16), dim3(256), 0, stream>>>(hpe, wv16, bv, vt);

    flash_kernel<<<dim3(32, 32), dim3(256), 0, stream>>>(qb, kb16, vt, pbuf, ao);

    gemm_nt<2><<<dim3(32, 16), dim3(256), 0, stream>>>(ao, wo16, bo, d_out);
}

// Round 3
// 247.077 us; speedup vs baseline: 1.2567x; 1.0720x over previous
//
#include <hip/hip_runtime.h>

typedef _Float16 h8 __attribute__((ext_vector_type(8)));
typedef _Float16 h4 __attribute__((ext_vector_type(4)));
typedef float f32x4 __attribute__((ext_vector_type(4)));

#define NSEQ 2048
#define DMODEL 1024
#define HD 64
#define C2 0.1803368801111244f   // 0.125 * log2(e)

// ---------------- workspace layout (bytes) ----------------
#define OFF_HPE  (size_t)0           // 4096x1024 f16 = 8MB
#define OFF_WQ   (size_t)8388608     // 1024x1024 f16 = 2MB
#define OFF_WK   (size_t)10485760
#define OFF_WV   (size_t)12582912
#define OFF_WO   (size_t)14680064
#define OFF_Q    (size_t)16777216    // 4096x1024 f16 = 8MB
#define OFF_K    (size_t)25165824
#define OFF_VT   (size_t)33554432    // [2][1024][2048] f16 = 8MB (V^T per head)
#define OFF_AO   (size_t)41943040    // 4096x1024 f16 = 8MB
#define OFF_PB   (size_t)50331648    // [2][2048] f32 (log2-domain bias)

#define GLL(g, l) __builtin_amdgcn_global_load_lds( \
    (const __attribute__((address_space(1))) unsigned int*)(const void*)(g), \
    (__attribute__((address_space(3))) unsigned int*)(l), 16, 0, 0)

#if __has_builtin(__builtin_amdgcn_mfma_f32_16x16x16f16)
#define HAVE_MFMA16 1
#else
#define HAVE_MFMA16 0
#endif

// ---------------- prep kernels ----------------
__global__ void hpe_kernel(const float* __restrict__ h, _Float16* __restrict__ hpe) {
    int idx = blockIdx.x * blockDim.x + threadIdx.x;   // over [4096][512] sin/cos pairs
    int row = idx >> 9;
    int i2  = idx & 511;
    int n = row & (NSEQ - 1);
    const float kTerm = -9.210340371976184f / 1024.0f; // -ln(10000)/1024
    float div = expf((float)(2 * i2) * kTerm);
    float ang = (float)n * div;
    float s = sinf(ang), c = cosf(ang);
    int base = row * DMODEL + 2 * i2;
    hpe[base]     = (_Float16)(h[base] + s);
    hpe[base + 1] = (_Float16)(h[base + 1] + c);
}

// fused cast of all 4 weight matrices (f32 -> f16), 4 x 1M elements, float4 per thread
__global__ void cast4_kernel(const float* __restrict__ w0, const float* __restrict__ w1,
                             const float* __restrict__ w2, const float* __restrict__ w3,
                             _Float16* __restrict__ d0, _Float16* __restrict__ d1,
                             _Float16* __restrict__ d2, _Float16* __restrict__ d3) {
    int i = blockIdx.x * blockDim.x + threadIdx.x;     // 0 .. 4*262144-1
    int which = i >> 18, idx = i & 262143;
    const float* s = which == 0 ? w0 : which == 1 ? w1 : which == 2 ? w2 : w3;
    _Float16* d    = which == 0 ? d0 : which == 1 ? d1 : which == 2 ? d2 : d3;
    float4 v = ((const float4*)s)[idx];
    union { _Float16 hh[4]; uint2 u; } o;
    o.hh[0] = (_Float16)v.x; o.hh[1] = (_Float16)v.y;
    o.hh[2] = (_Float16)v.z; o.hh[3] = (_Float16)v.w;
    ((uint2*)d)[idx] = o.u;
}

// log2-domain key bias: pb = pbs * log2(probs + 1e-8)
__global__ void pb_kernel(const float* __restrict__ probs, const float* __restrict__ pbs,
                          float* __restrict__ pb) {
    int i = blockIdx.x * blockDim.x + threadIdx.x;     // 4096
    pb[i] = pbs[0] * log2f(probs[i] + 1e-8f);
}

// ---------------- fused QKV GEMM: 128x128 tile, m97 structure ----------------
// C[4096][3072] = A @ [Wq;Wk;Wv]^T + bias.  blockIdx.y: 0-7 -> Q, 8-15 -> K, 16-23 -> V^T.
__global__ __launch_bounds__(256) void gemm_qkv(
    const _Float16* __restrict__ A,
    const _Float16* __restrict__ Wqp, const _Float16* __restrict__ Wkp, const _Float16* __restrict__ Wvp,
    const float* __restrict__ bqp, const float* __restrict__ bkp, const float* __restrict__ bvp,
    _Float16* __restrict__ qb, _Float16* __restrict__ kb, _Float16* __restrict__ vt)
{
    __shared__ __align__(16) _Float16 As[128][64];   // 16KB
    __shared__ __align__(16) _Float16 Bs[128][64];   // 16KB
    int widx = blockIdx.y >> 3;
    const _Float16* W = widx == 0 ? Wqp : widx == 1 ? Wkp : Wvp;
    const float* bias = widx == 0 ? bqp : widx == 1 ? bkp : bvp;
    int tm = blockIdx.x * 128;
    int tn = (blockIdx.y & 7) * 128;
    int t = threadIdx.x;
    int wave = t >> 6, lane = t & 63;
    int wr = (wave >> 1) * 64, wc = (wave & 1) * 64;
    int lr = lane & 15, lg = lane >> 4;

    f32x4 acc[4][4] = {};

    int grow = lane >> 3;
    int gcol = (lane & 7) * 8;
    const _Float16* Aptr = A + (size_t)(tm + wave * 8 + grow) * DMODEL + gcol;
    const _Float16* Wptr = W + (size_t)(tn + wave * 8 + grow) * DMODEL + gcol;

    for (int k0 = 0; k0 < DMODEL; k0 += 64) {
        __syncthreads();
        #pragma unroll
        for (int i = 0; i < 4; ++i)
            GLL(Aptr + (size_t)i * 32 * DMODEL + k0, &As[i * 32 + wave * 8][0]);
        #pragma unroll
        for (int i = 0; i < 4; ++i)
            GLL(Wptr + (size_t)i * 32 * DMODEL + k0, &Bs[i * 32 + wave * 8][0]);
        __syncthreads();
        #pragma unroll
        for (int kk = 0; kk < 2; ++kk) {
            h8 af[4], bf[4];
            #pragma unroll
            for (int mi = 0; mi < 4; ++mi) af[mi] = *(const h8*)&As[wr + mi * 16 + lr][kk * 32 + lg * 8];
            #pragma unroll
            for (int ni = 0; ni < 4; ++ni) bf[ni] = *(const h8*)&Bs[wc + ni * 16 + lr][kk * 32 + lg * 8];
            #pragma unroll
            for (int mi = 0; mi < 4; ++mi)
                #pragma unroll
                for (int ni = 0; ni < 4; ++ni)
                    acc[mi][ni] = __builtin_amdgcn_mfma_f32_16x16x32_f16(af[mi], bf[ni], acc[mi][ni], 0, 0, 0);
        }
    }

    #pragma unroll
    for (int mi = 0; mi < 4; ++mi)
        #pragma unroll
        for (int ni = 0; ni < 4; ++ni) {
            int col = tn + wc + ni * 16 + lr;     // 0..1023 within this W
            float bv = bias[col];
            if (widx < 2) {
                _Float16* dst = widx == 0 ? qb : kb;
                #pragma unroll
                for (int j = 0; j < 4; ++j) {
                    int row = tm + wr + mi * 16 + lg * 4 + j;
                    dst[(size_t)row * DMODEL + col] = (_Float16)(acc[mi][ni][j] + bv);
                }
            } else {
                // V^T: vt[(b*1024 + col)*2048 + n], n consecutive over j -> packed 8B store
                int row0 = tm + wr + mi * 16 + lg * 4;
                int b = row0 >> 11, n0 = row0 & 2047;
                h4 pk;
                #pragma unroll
                for (int j = 0; j < 4; ++j) pk[j] = (_Float16)(acc[mi][ni][j] + bv);
                *(h4*)&vt[((size_t)b * 1024 + col) * 2048 + n0] = pk;
            }
        }
}

// ---------------- AO GEMM: C[4096][1024] f32 = A @ Wo^T + bo ; 64x128 tile ----------------
__global__ __launch_bounds__(256) void gemm_ao(
    const _Float16* __restrict__ A, const _Float16* __restrict__ W,
    const float* __restrict__ bias, float* __restrict__ C)
{
    __shared__ __align__(16) _Float16 As[64][64];    // 8KB
    __shared__ __align__(16) _Float16 Bs[128][64];   // 16KB
    int tm = blockIdx.x * 64;
    int tn = blockIdx.y * 128;
    int t = threadIdx.x;
    int wave = t >> 6, lane = t & 63;
    int wr = (wave >> 1) * 32, wc = (wave & 1) * 64;
    int lr = lane & 15, lg = lane >> 4;

    f32x4 acc[2][4] = {};

    int grow = lane >> 3;
    int gcol = (lane & 7) * 8;
    const _Float16* Aptr = A + (size_t)(tm + wave * 8 + grow) * DMODEL + gcol;
    const _Float16* Wptr = W + (size_t)(tn + wave * 8 + grow) * DMODEL + gcol;

    for (int k0 = 0; k0 < DMODEL; k0 += 64) {
        __syncthreads();
        #pragma unroll
        for (int i = 0; i < 2; ++i)
            GLL(Aptr + (size_t)i * 32 * DMODEL + k0, &As[i * 32 + wave * 8][0]);
        #pragma unroll
        for (int i = 0; i < 4; ++i)
            GLL(Wptr + (size_t)i * 32 * DMODEL + k0, &Bs[i * 32 + wave * 8][0]);
        __syncthreads();
        #pragma unroll
        for (int kk = 0; kk < 2; ++kk) {
            h8 af[2], bf[4];
            #pragma unroll
            for (int mi = 0; mi < 2; ++mi) af[mi] = *(const h8*)&As[wr + mi * 16 + lr][kk * 32 + lg * 8];
            #pragma unroll
            for (int ni = 0; ni < 4; ++ni) bf[ni] = *(const h8*)&Bs[wc + ni * 16 + lr][kk * 32 + lg * 8];
            #pragma unroll
            for (int mi = 0; mi < 2; ++mi)
                #pragma unroll
                for (int ni = 0; ni < 4; ++ni)
                    acc[mi][ni] = __builtin_amdgcn_mfma_f32_16x16x32_f16(af[mi], bf[ni], acc[mi][ni], 0, 0, 0);
        }
    }

    #pragma unroll
    for (int mi = 0; mi < 2; ++mi)
        #pragma unroll
        for (int ni = 0; ni < 4; ++ni)
            #pragma unroll
            for (int j = 0; j < 4; ++j) {
                int row = tm + wr + mi * 16 + lg * 4 + j;
                int col = tn + wc + ni * 16 + lr;
                C[(size_t)row * DMODEL + col] = acc[mi][ni][j] + bias[col];
            }
}

// ---------------- flash attention v3 ----------------
// XOR-swizzled linear K/V tiles; P kept in registers (mfma 16x16x16 PV).
// grid (32 q-tiles of 64, 32 bh); 256 threads = 4 waves; wave owns 16 q-rows; KV tile 64.
#define QT 64
#define KT 64

// byte offset into a [64 rows][128B] tile with m214 XOR swizzle
#define SWZ(row, bytecol) ((row) * 128 + ((bytecol) ^ (((row) & 7) << 4)))

__global__ __launch_bounds__(256, 4) void flash_kernel(
    const _Float16* __restrict__ Qb,   // [4096][1024]
    const _Float16* __restrict__ Kb,   // [4096][1024]
    const _Float16* __restrict__ Vt,   // [2][1024][2048]
    const float* __restrict__ pb,      // [2][2048] log2-domain
    _Float16* __restrict__ AO)         // [4096][1024]
{
    __shared__ __align__(16) char KsB[64 * 128];       // 8KB  K tile [k][d]
    __shared__ __align__(16) char VsB[64 * 128];       // 8KB  V^T tile [d][k]
#if !HAVE_MFMA16
    __shared__ __align__(16) _Float16 Ps[4][16][72];   // fallback P staging
#endif
    int bh = blockIdx.y;
    int b = bh >> 4, h = bh & 15;
    int q0 = blockIdx.x * QT;
    int t = threadIdx.x, wave = t >> 6, lane = t & 63;
    int lr = lane & 15, lg = lane >> 4;

    const _Float16* Khead  = Kb + (size_t)b * NSEQ * DMODEL + h * HD;
    const _Float16* Vthead = Vt + ((size_t)b * 1024 + h * HD) * NSEQ;
    const float* pbb = pb + b * NSEQ;

    // Q fragment in registers (B-operand): lane holds Q row q = q0 + wave*16 + lr
    const _Float16* Qrow = Qb + ((size_t)b * NSEQ + q0 + wave * 16 + lr) * DMODEL + h * HD;
    h8 qf0 = *(const h8*)&Qrow[lg * 8];
    h8 qf1 = *(const h8*)&Qrow[32 + lg * 8];

    float mrun = -INFINITY, lrun = 0.f;   // softmax state for q = lr (dup across lg)
    f32x4 oacc[4] = {};                   // O[q = lg*4+j][d = ni*16+lr]

    int srow = t >> 2;                    // staging row 0..63
    int sc = (t & 3) * 32;                // staging byte col {0,32,64,96}

    for (int k0 = 0; k0 < NSEQ; k0 += KT) {
        f32x4 pbv[4];
        #pragma unroll
        for (int ci = 0; ci < 4; ++ci)
            pbv[ci] = *(const f32x4*)&pbb[k0 + ci * 16 + lg * 4];

        __syncthreads();
        *(h8*)(KsB + SWZ(srow, sc))      = *(const h8*)&Khead[(size_t)(k0 + srow) * DMODEL + (sc >> 1)];
        *(h8*)(KsB + SWZ(srow, sc + 16)) = *(const h8*)&Khead[(size_t)(k0 + srow) * DMODEL + (sc >> 1) + 8];
        *(h8*)(VsB + SWZ(srow, sc))      = *(const h8*)&Vthead[(size_t)srow * NSEQ + k0 + (sc >> 1)];
        *(h8*)(VsB + SWZ(srow, sc + 16)) = *(const h8*)&Vthead[(size_t)srow * NSEQ + k0 + (sc >> 1) + 8];
        __syncthreads();

        // S^T = K Q^T : lane holds S[q=lr][k = ci*16 + lg*4 + j]
        f32x4 s[4] = {};
        #pragma unroll
        for (int ci = 0; ci < 4; ++ci) {
            h8 kf = *(const h8*)(KsB + SWZ(ci * 16 + lr, lg * 16));
            s[ci] = __builtin_amdgcn_mfma_f32_16x16x32_f16(kf, qf0, s[ci], 0, 0, 0);
        }
        #pragma unroll
        for (int ci = 0; ci < 4; ++ci) {
            h8 kf = *(const h8*)(KsB + SWZ(ci * 16 + lr, 64 + lg * 16));
            s[ci] = __builtin_amdgcn_mfma_f32_16x16x32_f16(kf, qf1, s[ci], 0, 0, 0);
        }

        // log2-domain scores; lane-local row max
        float p[4][4];
        float sm = -INFINITY;
        #pragma unroll
        for (int ci = 0; ci < 4; ++ci)
            #pragma unroll
            for (int j = 0; j < 4; ++j) {
                float vv = fmaf(s[ci][j], C2, pbv[ci][j]);
                p[ci][j] = vv;
                sm = fmaxf(sm, vv);
            }
        sm = fmaxf(sm, __shfl_xor(sm, 16));
        sm = fmaxf(sm, __shfl_xor(sm, 32));
        float newm = fmaxf(mrun, sm);
        float fs = __builtin_amdgcn_exp2f(mrun - newm);
        float rs = 0.f;
        #pragma unroll
        for (int ci = 0; ci < 4; ++ci)
            #pragma unroll
            for (int j = 0; j < 4; ++j) {
                float e = __builtin_amdgcn_exp2f(p[ci][j] - newm);
                p[ci][j] = e;
                rs += e;
            }
        rs += __shfl_xor(rs, 16);
        rs += __shfl_xor(rs, 32);
        lrun = lrun * fs + rs;
        mrun = newm;

        // rescale O by fs of its q-row (source lane: lr = q-local)
        #pragma unroll
        for (int j = 0; j < 4; ++j) {
            float fsj = __shfl(fs, (lane & 48) | (lg * 4 + j), 64);
            #pragma unroll
            for (int ni = 0; ni < 4; ++ni) oacc[ni][j] *= fsj;
        }

#if HAVE_MFMA16
        // P already in A-operand layout for 16x16x16: A[row=lr][k=lg*4+j]
        #pragma unroll
        for (int ci = 0; ci < 4; ++ci) {
            h4 pa;
            #pragma unroll
            for (int j = 0; j < 4; ++j) pa[j] = (_Float16)p[ci][j];
            #pragma unroll
            for (int ni = 0; ni < 4; ++ni) {
                h4 vf = *(const h4*)(VsB + SWZ(ni * 16 + lr, ci * 32 + lg * 8));
                oacc[ni] = __builtin_amdgcn_mfma_f32_16x16x16f16(pa, vf, oacc[ni], 0, 0, 0);
            }
        }
#else
        #pragma unroll
        for (int ci = 0; ci < 4; ++ci) {
            union { _Float16 hh[4]; uint2 u; } pk;
            #pragma unroll
            for (int j = 0; j < 4; ++j) pk.hh[j] = (_Float16)p[ci][j];
            *(uint2*)&Ps[wave][lr][ci * 16 + lg * 4] = pk.u;
        }
        asm volatile("s_waitcnt lgkmcnt(0)" ::: "memory");
        __builtin_amdgcn_sched_barrier(0);
        #pragma unroll
        for (int kb2 = 0; kb2 < 2; ++kb2) {
            h8 pa = *(const h8*)&Ps[wave][lr][kb2 * 32 + lg * 8];
            #pragma unroll
            for (int ni = 0; ni < 4; ++ni) {
                h8 vf = *(const h8*)(VsB + SWZ(ni * 16 + lr, kb2 * 64 + lg * 16));
                oacc[ni] = __builtin_amdgcn_mfma_f32_16x16x32_f16(pa, vf, oacc[ni], 0, 0, 0);
            }
        }
#endif
    }

    // epilogue: divide by lrun of the row, write out
    #pragma unroll
    for (int j = 0; j < 4; ++j) {
        float lj = __shfl(lrun, (lane & 48) | (lg * 4 + j), 64);
        float inv = 1.0f / lj;
        int row = q0 + wave * 16 + lg * 4 + j;
        #pragma unroll
        for (int ni = 0; ni < 4; ++ni)
            AO[((size_t)b * NSEQ + row) * DMODEL + h * HD + ni * 16 + lr] = (_Float16)(oacc[ni][j] * inv);
    }
}

// ---------------- launcher ----------------
extern "C" void kernel_launch(void* const* d_in, const int* in_sizes, int n_in,
                              void* d_out, int out_size, void* d_ws, size_t ws_size,
                              hipStream_t stream) {
    const float* h    = (const float*)d_in[0];
    const float* prob = (const float*)d_in[1];
    const float* Wq   = (const float*)d_in[2];
    const float* bq   = (const float*)d_in[3];
    const float* Wk   = (const float*)d_in[4];
    const float* bk   = (const float*)d_in[5];
    const float* Wv   = (const float*)d_in[6];
    const float* bv   = (const float*)d_in[7];
    const float* Wo   = (const float*)d_in[8];
    const float* bo   = (const float*)d_in[9];
    const float* pbs  = (const float*)d_in[10];

    char* ws = (char*)d_ws;
    _Float16* hpe  = (_Float16*)(ws + OFF_HPE);
    _Float16* wq16 = (_Float16*)(ws + OFF_WQ);
    _Float16* wk16 = (_Float16*)(ws + OFF_WK);
    _Float16* wv16 = (_Float16*)(ws + OFF_WV);
    _Float16* wo16 = (_Float16*)(ws + OFF_WO);
    _Float16* qb   = (_Float16*)(ws + OFF_Q);
    _Float16* kb16 = (_Float16*)(ws + OFF_K);
    _Float16* vt   = (_Float16*)(ws + OFF_VT);
    _Float16* ao   = (_Float16*)(ws + OFF_AO);
    float*    pbuf = (float*)(ws + OFF_PB);

    hpe_kernel<<<dim3(8192), dim3(256), 0, stream>>>(h, hpe);
    cast4_kernel<<<dim3(4096), dim3(256), 0, stream>>>(Wq, Wk, Wv, Wo, wq16, wk16, wv16, wo16);
    pb_kernel<<<dim3(16), dim3(256), 0, stream>>>(prob, pbs, pbuf);

    gemm_qkv<<<dim3(32, 24), dim3(256), 0, stream>>>(hpe, wq16, wk16, wv16, bq, bk, bv, qb, kb16, vt);

    flash_kernel<<<dim3(32, 32), dim3(256), 0, stream>>>(qb, kb16, vt, pbuf, ao);

    gemm_ao<<<dim3(64, 8), dim3(256), 0, stream>>>(ao, wo16, bo, (float*)d_out);
}

// Round 6
// 246.135 us; speedup vs baseline: 1.2615x; 1.0038x over previous
//
#include <hip/hip_runtime.h>

typedef _Float16 h8 __attribute__((ext_vector_type(8)));
typedef _Float16 h4 __attribute__((ext_vector_type(4)));
typedef __fp16 fp16x2 __attribute__((ext_vector_type(2)));
typedef float f32x4 __attribute__((ext_vector_type(4)));

#define NSEQ 2048
#define DMODEL 1024
#define HD 64
#define C2 0.1803368801111244f   // 0.125 * log2(e), folded into Wq/bq

// ---------------- workspace layout (bytes) ----------------
#define OFF_HPE  (size_t)0           // 4096x1024 f16 = 8MB
#define OFF_WQ   (size_t)8388608     // 1024x1024 f16 = 2MB (pre-scaled by C2)
#define OFF_WK   (size_t)10485760
#define OFF_WV   (size_t)12582912
#define OFF_WO   (size_t)14680064
#define OFF_Q    (size_t)16777216    // 4096x1024 f16 = 8MB (Q pre-scaled by C2)
#define OFF_K    (size_t)25165824
#define OFF_VT   (size_t)33554432    // [2][1024][2048] f16 = 8MB (V^T per head)
#define OFF_AO   (size_t)41943040    // 4096x1024 f16 = 8MB
#define OFF_PB   (size_t)50331648    // [2][2048] f32 (log2-domain bias)

#define GLL(g, l) __builtin_amdgcn_global_load_lds( \
    (const __attribute__((address_space(1))) unsigned int*)(const void*)(g), \
    (__attribute__((address_space(3))) unsigned int*)(l), 16, 0, 0)

// ---------------- prep kernels ----------------
// h + sinusoidal PE -> f16.  Thread = 8 halfs (4 sin/cos pairs). HW trig in revolutions.
__global__ void hpe_kernel(const float* __restrict__ h, _Float16* __restrict__ hpe) {
    int idx = blockIdx.x * blockDim.x + threadIdx.x;   // 0 .. 4096*128-1
    int row = idx >> 7;
    int c8 = (idx & 127) * 8;                          // col of first half
    int n = row & (NSEQ - 1);
    const float kL = -0.025952563241307517f;           // -log2(10000)/512
    const float kInv2Pi = 0.15915494309189535f;
    union { float4 f4[2]; float f[8]; } in;
    in.f4[0] = *(const float4*)&h[(size_t)row * DMODEL + c8];
    in.f4[1] = *(const float4*)&h[(size_t)row * DMODEL + c8 + 4];
    union { _Float16 hh[8]; uint4 u; } out;
    #pragma unroll
    for (int p = 0; p < 4; ++p) {
        int i2 = (c8 >> 1) + p;
        float div = __builtin_amdgcn_exp2f((float)i2 * kL);
        float rev = (float)n * div * kInv2Pi;
        float rf = __builtin_amdgcn_fractf(rev);
        float s = __builtin_amdgcn_sinf(rf);
        float c = __builtin_amdgcn_cosf(rf);
        out.hh[2 * p]     = (_Float16)(in.f[2 * p] + s);
        out.hh[2 * p + 1] = (_Float16)(in.f[2 * p + 1] + c);
    }
    *(uint4*)&hpe[(size_t)row * DMODEL + c8] = out.u;
}

// fused cast of all 4 weight matrices (f32 -> f16); Wq additionally scaled by C2
__global__ void cast4_kernel(const float* __restrict__ w0, const float* __restrict__ w1,
                             const float* __restrict__ w2, const float* __restrict__ w3,
                             _Float16* __restrict__ d0, _Float16* __restrict__ d1,
                             _Float16* __restrict__ d2, _Float16* __restrict__ d3) {
    int i = blockIdx.x * blockDim.x + threadIdx.x;     // 0 .. 4*262144-1
    int which = i >> 18, idx = i & 262143;
    const float* s = which == 0 ? w0 : which == 1 ? w1 : which == 2 ? w2 : w3;
    _Float16* d    = which == 0 ? d0 : which == 1 ? d1 : which == 2 ? d2 : d3;
    float sc = which == 0 ? C2 : 1.0f;
    float4 v = ((const float4*)s)[idx];
    union { _Float16 hh[4]; uint2 u; } o;
    o.hh[0] = (_Float16)(v.x * sc); o.hh[1] = (_Float16)(v.y * sc);
    o.hh[2] = (_Float16)(v.z * sc); o.hh[3] = (_Float16)(v.w * sc);
    ((uint2*)d)[idx] = o.u;
}

// log2-domain key bias: pb = pbs * log2(probs + 1e-8)
__global__ void pb_kernel(const float* __restrict__ probs, const float* __restrict__ pbs,
                          float* __restrict__ pb) {
    int i = blockIdx.x * blockDim.x + threadIdx.x;     // 4096
    pb[i] = pbs[0] * log2f(probs[i] + 1e-8f);
}

// ---------------- fused QKV GEMM: 128x128 tile, m97 structure ----------------
// blockIdx.y: 0-7 -> Q (bias*C2), 8-15 -> K, 16-23 -> V^T.
__global__ __launch_bounds__(256) void gemm_qkv(
    const _Float16* __restrict__ A,
    const _Float16* __restrict__ Wqp, const _Float16* __restrict__ Wkp, const _Float16* __restrict__ Wvp,
    const float* __restrict__ bqp, const float* __restrict__ bkp, const float* __restrict__ bvp,
    _Float16* __restrict__ qb, _Float16* __restrict__ kb, _Float16* __restrict__ vt)
{
    __shared__ __align__(16) _Float16 As[128][64];   // 16KB
    __shared__ __align__(16) _Float16 Bs[128][64];   // 16KB
    int widx = blockIdx.y >> 3;
    const _Float16* W = widx == 0 ? Wqp : widx == 1 ? Wkp : Wvp;
    const float* bias = widx == 0 ? bqp : widx == 1 ? bkp : bvp;
    float bscale = widx == 0 ? C2 : 1.0f;
    int tm = blockIdx.x * 128;
    int tn = (blockIdx.y & 7) * 128;
    int t = threadIdx.x;
    int wave = t >> 6, lane = t & 63;
    int wr = (wave >> 1) * 64, wc = (wave & 1) * 64;
    int lr = lane & 15, lg = lane >> 4;

    f32x4 acc[4][4] = {};

    int grow = lane >> 3;
    int gcol = (lane & 7) * 8;
    const _Float16* Aptr = A + (size_t)(tm + wave * 8 + grow) * DMODEL + gcol;
    const _Float16* Wptr = W + (size_t)(tn + wave * 8 + grow) * DMODEL + gcol;

    for (int k0 = 0; k0 < DMODEL; k0 += 64) {
        __syncthreads();
        #pragma unroll
        for (int i = 0; i < 4; ++i)
            GLL(Aptr + (size_t)i * 32 * DMODEL + k0, &As[i * 32 + wave * 8][0]);
        #pragma unroll
        for (int i = 0; i < 4; ++i)
            GLL(Wptr + (size_t)i * 32 * DMODEL + k0, &Bs[i * 32 + wave * 8][0]);
        __syncthreads();
        #pragma unroll
        for (int kk = 0; kk < 2; ++kk) {
            h8 af[4], bf[4];
            #pragma unroll
            for (int mi = 0; mi < 4; ++mi) af[mi] = *(const h8*)&As[wr + mi * 16 + lr][kk * 32 + lg * 8];
            #pragma unroll
            for (int ni = 0; ni < 4; ++ni) bf[ni] = *(const h8*)&Bs[wc + ni * 16 + lr][kk * 32 + lg * 8];
            #pragma unroll
            for (int mi = 0; mi < 4; ++mi)
                #pragma unroll
                for (int ni = 0; ni < 4; ++ni)
                    acc[mi][ni] = __builtin_amdgcn_mfma_f32_16x16x32_f16(af[mi], bf[ni], acc[mi][ni], 0, 0, 0);
        }
    }

    #pragma unroll
    for (int mi = 0; mi < 4; ++mi)
        #pragma unroll
        for (int ni = 0; ni < 4; ++ni) {
            int col = tn + wc + ni * 16 + lr;
            float bv = bias[col] * bscale;
            if (widx < 2) {
                _Float16* dst = widx == 0 ? qb : kb;
                #pragma unroll
                for (int j = 0; j < 4; ++j) {
                    int row = tm + wr + mi * 16 + lg * 4 + j;
                    dst[(size_t)row * DMODEL + col] = (_Float16)(acc[mi][ni][j] + bv);
                }
            } else {
                int row0 = tm + wr + mi * 16 + lg * 4;
                int b = row0 >> 11, n0 = row0 & 2047;
                h4 pk;
                #pragma unroll
                for (int j = 0; j < 4; ++j) pk[j] = (_Float16)(acc[mi][ni][j] + bv);
                *(h4*)&vt[((size_t)b * 1024 + col) * 2048 + n0] = pk;
            }
        }
}

// ---------------- AO GEMM: C[4096][1024] f32 = A @ Wo^T + bo ; 64x128 tile ----------------
__global__ __launch_bounds__(256) void gemm_ao(
    const _Float16* __restrict__ A, const _Float16* __restrict__ W,
    const float* __restrict__ bias, float* __restrict__ C)
{
    __shared__ __align__(16) _Float16 As[64][64];    // 8KB
    __shared__ __align__(16) _Float16 Bs[128][64];   // 16KB
    int tm = blockIdx.x * 64;
    int tn = blockIdx.y * 128;
    int t = threadIdx.x;
    int wave = t >> 6, lane = t & 63;
    int wr = (wave >> 1) * 32, wc = (wave & 1) * 64;
    int lr = lane & 15, lg = lane >> 4;

    f32x4 acc[2][4] = {};

    int grow = lane >> 3;
    int gcol = (lane & 7) * 8;
    const _Float16* Aptr = A + (size_t)(tm + wave * 8 + grow) * DMODEL + gcol;
    const _Float16* Wptr = W + (size_t)(tn + wave * 8 + grow) * DMODEL + gcol;

    for (int k0 = 0; k0 < DMODEL; k0 += 64) {
        __syncthreads();
        #pragma unroll
        for (int i = 0; i < 2; ++i)
            GLL(Aptr + (size_t)i * 32 * DMODEL + k0, &As[i * 32 + wave * 8][0]);
        #pragma unroll
        for (int i = 0; i < 4; ++i)
            GLL(Wptr + (size_t)i * 32 * DMODEL + k0, &Bs[i * 32 + wave * 8][0]);
        __syncthreads();
        #pragma unroll
        for (int kk = 0; kk < 2; ++kk) {
            h8 af[2], bf[4];
            #pragma unroll
            for (int mi = 0; mi < 2; ++mi) af[mi] = *(const h8*)&As[wr + mi * 16 + lr][kk * 32 + lg * 8];
            #pragma unroll
            for (int ni = 0; ni < 4; ++ni) bf[ni] = *(const h8*)&Bs[wc + ni * 16 + lr][kk * 32 + lg * 8];
            #pragma unroll
            for (int mi = 0; mi < 2; ++mi)
                #pragma unroll
                for (int ni = 0; ni < 4; ++ni)
                    acc[mi][ni] = __builtin_amdgcn_mfma_f32_16x16x32_f16(af[mi], bf[ni], acc[mi][ni], 0, 0, 0);
        }
    }

    #pragma unroll
    for (int mi = 0; mi < 2; ++mi)
        #pragma unroll
        for (int ni = 0; ni < 4; ++ni)
            #pragma unroll
            for (int j = 0; j < 4; ++j) {
                int row = tm + wr + mi * 16 + lg * 4 + j;
                int col = tn + wc + ni * 16 + lr;
                C[(size_t)row * DMODEL + col] = acc[mi][ni][j] + bias[col];
            }
}

// ---------------- flash attention v4 ----------------
// Q pre-scaled by C2; bias enters via MFMA C-init; row-sum via ones-column MFMA;
// skip-rescale when max doesn't grow; PV via per-wave Ps LDS with 16x16x32 MFMA.
#define QT 64
#define KT 64

// byte offset into a [64 rows][128B] tile with m214 XOR swizzle
#define SWZ(row, bytecol) ((row) * 128 + ((bytecol) ^ (((row) & 7) << 4)))

__global__ __launch_bounds__(256, 4) void flash_kernel(
    const _Float16* __restrict__ Qb,   // [4096][1024], pre-scaled by C2
    const _Float16* __restrict__ Kb,   // [4096][1024]
    const _Float16* __restrict__ Vt,   // [2][1024][2048]
    const float* __restrict__ pb,      // [2][2048] log2-domain
    _Float16* __restrict__ AO)         // [4096][1024]
{
    __shared__ __align__(16) char KsB[64 * 128];       // 8KB  K tile [k][d]
    __shared__ __align__(16) char VsB[64 * 128];       // 8KB  V^T tile [d][k]
    __shared__ __align__(16) _Float16 Ps[4][16][72];   // 9KB  per-wave P (2-way floor)
    int bh = blockIdx.y;
    int b = bh >> 4, h = bh & 15;
    int q0 = blockIdx.x * QT;
    int t = threadIdx.x, wave = t >> 6, lane = t & 63;
    int lr = lane & 15, lg = lane >> 4;

    const _Float16* Khead  = Kb + (size_t)b * NSEQ * DMODEL + h * HD;
    const _Float16* Vthead = Vt + ((size_t)b * 1024 + h * HD) * NSEQ;
    const float* pbb = pb + b * NSEQ;

    // Q fragment in registers (B-operand): lane holds Q row q = q0 + wave*16 + lr
    const _Float16* Qrow = Qb + ((size_t)b * NSEQ + q0 + wave * 16 + lr) * DMODEL + h * HD;
    h8 qf0 = *(const h8*)&Qrow[lg * 8];
    h8 qf1 = *(const h8*)&Qrow[32 + lg * 8];

    const h8 vones = { (_Float16)1, (_Float16)1, (_Float16)1, (_Float16)1,
                       (_Float16)1, (_Float16)1, (_Float16)1, (_Float16)1 };

    float mrun = -INFINITY;               // running max for q = lr (dup across lg)
    f32x4 oacc[4] = {};                   // O[q = lg*4+j][d = ni*16+lr]
    f32x4 lsum = {};                      // row-sum for q = lg*4+j (from ones-column MFMA)

    int srow = t >> 2;                    // staging row 0..63
    int sc = (t & 3) * 32;                // staging byte col {0,32,64,96}

    for (int k0 = 0; k0 < NSEQ; k0 += KT) {
        // per-key bias in S-layout (k = ci*16 + lg*4 + j)
        f32x4 s[4];
        #pragma unroll
        for (int ci = 0; ci < 4; ++ci)
            s[ci] = *(const f32x4*)&pbb[k0 + ci * 16 + lg * 4];

        __syncthreads();
        *(h8*)(KsB + SWZ(srow, sc))      = *(const h8*)&Khead[(size_t)(k0 + srow) * DMODEL + (sc >> 1)];
        *(h8*)(KsB + SWZ(srow, sc + 16)) = *(const h8*)&Khead[(size_t)(k0 + srow) * DMODEL + (sc >> 1) + 8];
        *(h8*)(VsB + SWZ(srow, sc))      = *(const h8*)&Vthead[(size_t)srow * NSEQ + k0 + (sc >> 1)];
        *(h8*)(VsB + SWZ(srow, sc + 16)) = *(const h8*)&Vthead[(size_t)srow * NSEQ + k0 + (sc >> 1) + 8];
        __syncthreads();

        // S^T = (C2*Q)K^T + bias : lane holds S[q=lr][k = ci*16 + lg*4 + j] (log2 domain)
        #pragma unroll
        for (int ci = 0; ci < 4; ++ci) {
            h8 kf = *(const h8*)(KsB + SWZ(ci * 16 + lr, lg * 16));
            s[ci] = __builtin_amdgcn_mfma_f32_16x16x32_f16(kf, qf0, s[ci], 0, 0, 0);
        }
        #pragma unroll
        for (int ci = 0; ci < 4; ++ci) {
            h8 kf = *(const h8*)(KsB + SWZ(ci * 16 + lr, 64 + lg * 16));
            s[ci] = __builtin_amdgcn_mfma_f32_16x16x32_f16(kf, qf1, s[ci], 0, 0, 0);
        }

        // row max (lane-local 16 + cross-lg)
        float sm = s[0][0];
        #pragma unroll
        for (int ci = 0; ci < 4; ++ci)
            #pragma unroll
            for (int j = 0; j < 4; ++j) sm = fmaxf(sm, s[ci][j]);
        sm = fmaxf(sm, __shfl_xor(sm, 16));
        sm = fmaxf(sm, __shfl_xor(sm, 32));

        bool need = __any(sm > mrun);
        float newm = need ? fmaxf(mrun, sm) : mrun;

        // P = exp2(s - newm) -> packed f16 (cvt_pkrtz) -> per-wave LDS
        #pragma unroll
        for (int ci = 0; ci < 4; ++ci) {
            fp16x2 a = __builtin_amdgcn_cvt_pkrtz(__builtin_amdgcn_exp2f(s[ci][0] - newm),
                                                  __builtin_amdgcn_exp2f(s[ci][1] - newm));
            fp16x2 b2 = __builtin_amdgcn_cvt_pkrtz(__builtin_amdgcn_exp2f(s[ci][2] - newm),
                                                   __builtin_amdgcn_exp2f(s[ci][3] - newm));
            union { fp16x2 hh[2]; uint2 u; } pk;
            pk.hh[0] = a; pk.hh[1] = b2;
            *(uint2*)&Ps[wave][lr][ci * 16 + lg * 4] = pk.u;
        }

        // V fragments (independent of Ps)
        h8 vf[2][4];
        #pragma unroll
        for (int kb = 0; kb < 2; ++kb)
            #pragma unroll
            for (int ni = 0; ni < 4; ++ni)
                vf[kb][ni] = *(const h8*)(VsB + SWZ(ni * 16 + lr, kb * 64 + lg * 16));

        // rescale O (and sum) only when the max grew (uniform branch)
        if (need) {
            float fs = __builtin_amdgcn_exp2f(mrun - newm);
            mrun = newm;
            #pragma unroll
            for (int j = 0; j < 4; ++j) {
                float fsj = __shfl(fs, (lane & 48) | (lg * 4 + j), 64);
                #pragma unroll
                for (int ni = 0; ni < 4; ++ni) oacc[ni][j] *= fsj;
                lsum[j] *= fsj;
            }
        }

        asm volatile("s_waitcnt lgkmcnt(0)" ::: "memory");

        // O += P @ V ; lsum += P @ 1
        #pragma unroll
        for (int kb = 0; kb < 2; ++kb) {
            h8 pa = *(const h8*)&Ps[wave][lr][kb * 32 + lg * 8];
            #pragma unroll
            for (int ni = 0; ni < 4; ++ni)
                oacc[ni] = __builtin_amdgcn_mfma_f32_16x16x32_f16(pa, vf[kb][ni], oacc[ni], 0, 0, 0);
            lsum = __builtin_amdgcn_mfma_f32_16x16x32_f16(pa, vones, lsum, 0, 0, 0);
        }
    }

    // epilogue: divide by row-sum (already in oacc layout), write out
    #pragma unroll
    for (int j = 0; j < 4; ++j) {
        float inv = 1.0f / lsum[j];
        int row = q0 + wave * 16 + lg * 4 + j;
        #pragma unroll
        for (int ni = 0; ni < 4; ++ni)
            AO[((size_t)b * NSEQ + row) * DMODEL + h * HD + ni * 16 + lr] = (_Float16)(oacc[ni][j] * inv);
    }
}

// ---------------- launcher ----------------
extern "C" void kernel_launch(void* const* d_in, const int* in_sizes, int n_in,
                              void* d_out, int out_size, void* d_ws, size_t ws_size,
                              hipStream_t stream) {
    const float* h    = (const float*)d_in[0];
    const float* prob = (const float*)d_in[1];
    const float* Wq   = (const float*)d_in[2];
    const float* bq   = (const float*)d_in[3];
    const float* Wk   = (const float*)d_in[4];
    const float* bk   = (const float*)d_in[5];
    const float* Wv   = (const float*)d_in[6];
    const float* bv   = (const float*)d_in[7];
    const float* Wo   = (const float*)d_in[8];
    const float* bo   = (const float*)d_in[9];
    const float* pbs  = (const float*)d_in[10];

    char* ws = (char*)d_ws;
    _Float16* hpe  = (_Float16*)(ws + OFF_HPE);
    _Float16* wq16 = (_Float16*)(ws + OFF_WQ);
    _Float16* wk16 = (_Float16*)(ws + OFF_WK);
    _Float16* wv16 = (_Float16*)(ws + OFF_WV);
    _Float16* wo16 = (_Float16*)(ws + OFF_WO);
    _Float16* qb   = (_Float16*)(ws + OFF_Q);
    _Float16* kb16 = (_Float16*)(ws + OFF_K);
    _Float16* vt   = (_Float16*)(ws + OFF_VT);
    _Float16* ao   = (_Float16*)(ws + OFF_AO);
    float*    pbuf = (float*)(ws + OFF_PB);

    hpe_kernel<<<dim3(2048), dim3(256), 0, stream>>>(h, hpe);
    cast4_kernel<<<dim3(4096), dim3(256), 0, stream>>>(Wq, Wk, Wv, Wo, wq16, wk16, wv16, wo16);
    pb_kernel<<<dim3(16), dim3(256), 0, stream>>>(prob, pbs, pbuf);

    gemm_qkv<<<dim3(32, 24), dim3(256), 0, stream>>>(hpe, wq16, wk16, wv16, bq, bk, bv, qb, kb16, vt);

    flash_kernel<<<dim3(32, 32), dim3(256), 0, stream>>>(qb, kb16, vt, pbuf, ao);

    gemm_ao<<<dim3(64, 8), dim3(256), 0, stream>>>(ao, wo16, bo, (float*)d_out);
}

// Round 7
// 233.809 us; speedup vs baseline: 1.3280x; 1.0527x over previous
//
#include <hip/hip_runtime.h>

typedef _Float16 h8 __attribute__((ext_vector_type(8)));
typedef _Float16 h4 __attribute__((ext_vector_type(4)));
typedef __fp16 fp16x2 __attribute__((ext_vector_type(2)));
typedef float f32x4 __attribute__((ext_vector_type(4)));

#define NSEQ 2048
#define DMODEL 1024
#define HD 64
#define C2 0.1803368801111244f   // 0.125 * log2(e), folded into Wq/bq

// ---------------- workspace layout (bytes) ----------------
#define OFF_HPE  (size_t)0           // 4096x1024 f16 = 8MB
#define OFF_WQ   (size_t)8388608     // 1024x1024 f16 = 2MB (pre-scaled by C2)
#define OFF_WK   (size_t)10485760
#define OFF_WV   (size_t)12582912
#define OFF_WO   (size_t)14680064
#define OFF_Q    (size_t)16777216    // 4096x1024 f16 = 8MB (Q pre-scaled by C2)
#define OFF_K    (size_t)25165824
#define OFF_VT   (size_t)33554432    // [2][1024][2048] f16 = 8MB (V^T per head)
#define OFF_AO   (size_t)41943040    // 4096x1024 f16 = 8MB
#define OFF_PB   (size_t)50331648    // [2][2048] f32 (log2-domain bias)

#define GLL(g, l) __builtin_amdgcn_global_load_lds( \
    (const __attribute__((address_space(1))) unsigned int*)(const void*)(g), \
    (__attribute__((address_space(3))) unsigned int*)(l), 16, 0, 0)

// ---------------- prep kernels ----------------
__global__ void hpe_kernel(const float* __restrict__ h, _Float16* __restrict__ hpe) {
    int idx = blockIdx.x * blockDim.x + threadIdx.x;   // 0 .. 4096*128-1
    int row = idx >> 7;
    int c8 = (idx & 127) * 8;
    int n = row & (NSEQ - 1);
    const float kL = -0.025952563241307517f;           // -log2(10000)/512
    const float kInv2Pi = 0.15915494309189535f;
    union { float4 f4[2]; float f[8]; } in;
    in.f4[0] = *(const float4*)&h[(size_t)row * DMODEL + c8];
    in.f4[1] = *(const float4*)&h[(size_t)row * DMODEL + c8 + 4];
    union { _Float16 hh[8]; uint4 u; } out;
    #pragma unroll
    for (int p = 0; p < 4; ++p) {
        int i2 = (c8 >> 1) + p;
        float div = __builtin_amdgcn_exp2f((float)i2 * kL);
        float rev = (float)n * div * kInv2Pi;
        float rf = __builtin_amdgcn_fractf(rev);
        float s = __builtin_amdgcn_sinf(rf);
        float c = __builtin_amdgcn_cosf(rf);
        out.hh[2 * p]     = (_Float16)(in.f[2 * p] + s);
        out.hh[2 * p + 1] = (_Float16)(in.f[2 * p + 1] + c);
    }
    *(uint4*)&hpe[(size_t)row * DMODEL + c8] = out.u;
}

__global__ void cast4_kernel(const float* __restrict__ w0, const float* __restrict__ w1,
                             const float* __restrict__ w2, const float* __restrict__ w3,
                             _Float16* __restrict__ d0, _Float16* __restrict__ d1,
                             _Float16* __restrict__ d2, _Float16* __restrict__ d3) {
    int i = blockIdx.x * blockDim.x + threadIdx.x;
    int which = i >> 18, idx = i & 262143;
    const float* s = which == 0 ? w0 : which == 1 ? w1 : which == 2 ? w2 : w3;
    _Float16* d    = which == 0 ? d0 : which == 1 ? d1 : which == 2 ? d2 : d3;
    float sc = which == 0 ? C2 : 1.0f;
    float4 v = ((const float4*)s)[idx];
    union { _Float16 hh[4]; uint2 u; } o;
    o.hh[0] = (_Float16)(v.x * sc); o.hh[1] = (_Float16)(v.y * sc);
    o.hh[2] = (_Float16)(v.z * sc); o.hh[3] = (_Float16)(v.w * sc);
    ((uint2*)d)[idx] = o.u;
}

__global__ void pb_kernel(const float* __restrict__ probs, const float* __restrict__ pbs,
                          float* __restrict__ pb) {
    int i = blockIdx.x * blockDim.x + threadIdx.x;     // 4096
    pb[i] = pbs[0] * log2f(probs[i] + 1e-8f);
}

// ---------------- fused QKV GEMM: 128x128 tile, m97 structure, XCD swizzle ----------------
__global__ __launch_bounds__(256) void gemm_qkv(
    const _Float16* __restrict__ A,
    const _Float16* __restrict__ Wqp, const _Float16* __restrict__ Wkp, const _Float16* __restrict__ Wvp,
    const float* __restrict__ bqp, const float* __restrict__ bkp, const float* __restrict__ bvp,
    _Float16* __restrict__ qb, _Float16* __restrict__ kb, _Float16* __restrict__ vt)
{
    __shared__ __align__(16) _Float16 As[128][64];   // 16KB
    __shared__ __align__(16) _Float16 Bs[128][64];   // 16KB
    // bijective XCD swizzle: 768 blocks = 8 XCD x 96
    int bid = blockIdx.x + 32 * blockIdx.y;
    int nf = (bid & 7) * 96 + (bid >> 3);
    int bx = nf & 31, byy = nf >> 5;
    int widx = byy >> 3;
    const _Float16* W = widx == 0 ? Wqp : widx == 1 ? Wkp : Wvp;
    const float* bias = widx == 0 ? bqp : widx == 1 ? bkp : bvp;
    float bscale = widx == 0 ? C2 : 1.0f;
    int tm = bx * 128;
    int tn = (byy & 7) * 128;
    int t = threadIdx.x;
    int wave = t >> 6, lane = t & 63;
    int wr = (wave >> 1) * 64, wc = (wave & 1) * 64;
    int lr = lane & 15, lg = lane >> 4;

    f32x4 acc[4][4] = {};

    int grow = lane >> 3;
    int gcol = (lane & 7) * 8;
    const _Float16* Aptr = A + (size_t)(tm + wave * 8 + grow) * DMODEL + gcol;
    const _Float16* Wptr = W + (size_t)(tn + wave * 8 + grow) * DMODEL + gcol;

    for (int k0 = 0; k0 < DMODEL; k0 += 64) {
        __syncthreads();
        #pragma unroll
        for (int i = 0; i < 4; ++i)
            GLL(Aptr + (size_t)i * 32 * DMODEL + k0, &As[i * 32 + wave * 8][0]);
        #pragma unroll
        for (int i = 0; i < 4; ++i)
            GLL(Wptr + (size_t)i * 32 * DMODEL + k0, &Bs[i * 32 + wave * 8][0]);
        __syncthreads();
        #pragma unroll
        for (int kk = 0; kk < 2; ++kk) {
            h8 af[4], bf[4];
            #pragma unroll
            for (int mi = 0; mi < 4; ++mi) af[mi] = *(const h8*)&As[wr + mi * 16 + lr][kk * 32 + lg * 8];
            #pragma unroll
            for (int ni = 0; ni < 4; ++ni) bf[ni] = *(const h8*)&Bs[wc + ni * 16 + lr][kk * 32 + lg * 8];
            #pragma unroll
            for (int mi = 0; mi < 4; ++mi)
                #pragma unroll
                for (int ni = 0; ni < 4; ++ni)
                    acc[mi][ni] = __builtin_amdgcn_mfma_f32_16x16x32_f16(af[mi], bf[ni], acc[mi][ni], 0, 0, 0);
        }
    }

    #pragma unroll
    for (int mi = 0; mi < 4; ++mi)
        #pragma unroll
        for (int ni = 0; ni < 4; ++ni) {
            int col = tn + wc + ni * 16 + lr;
            float bv = bias[col] * bscale;
            if (widx < 2) {
                _Float16* dst = widx == 0 ? qb : kb;
                #pragma unroll
                for (int j = 0; j < 4; ++j) {
                    int row = tm + wr + mi * 16 + lg * 4 + j;
                    dst[(size_t)row * DMODEL + col] = (_Float16)(acc[mi][ni][j] + bv);
                }
            } else {
                int row0 = tm + wr + mi * 16 + lg * 4;
                int b = row0 >> 11, n0 = row0 & 2047;
                h4 pk;
                #pragma unroll
                for (int j = 0; j < 4; ++j) pk[j] = (_Float16)(acc[mi][ni][j] + bv);
                *(h4*)&vt[((size_t)b * 1024 + col) * 2048 + n0] = pk;
            }
        }
}

// ---------------- AO GEMM: C[4096][1024] f32 = A @ Wo^T + bo ; 64x128 tile, XCD swizzle ----
__global__ __launch_bounds__(256) void gemm_ao(
    const _Float16* __restrict__ A, const _Float16* __restrict__ W,
    const float* __restrict__ bias, float* __restrict__ C)
{
    __shared__ __align__(16) _Float16 As[64][64];    // 8KB
    __shared__ __align__(16) _Float16 Bs[128][64];   // 16KB
    // bijective XCD swizzle: 512 blocks = 8 XCD x 64
    int bid = blockIdx.x + 64 * blockIdx.y;
    int nf = (bid & 7) * 64 + (bid >> 3);
    int tm = (nf & 63) * 64;
    int tn = (nf >> 6) * 128;
    int t = threadIdx.x;
    int wave = t >> 6, lane = t & 63;
    int wr = (wave >> 1) * 32, wc = (wave & 1) * 64;
    int lr = lane & 15, lg = lane >> 4;

    f32x4 acc[2][4] = {};

    int grow = lane >> 3;
    int gcol = (lane & 7) * 8;
    const _Float16* Aptr = A + (size_t)(tm + wave * 8 + grow) * DMODEL + gcol;
    const _Float16* Wptr = W + (size_t)(tn + wave * 8 + grow) * DMODEL + gcol;

    for (int k0 = 0; k0 < DMODEL; k0 += 64) {
        __syncthreads();
        #pragma unroll
        for (int i = 0; i < 2; ++i)
            GLL(Aptr + (size_t)i * 32 * DMODEL + k0, &As[i * 32 + wave * 8][0]);
        #pragma unroll
        for (int i = 0; i < 4; ++i)
            GLL(Wptr + (size_t)i * 32 * DMODEL + k0, &Bs[i * 32 + wave * 8][0]);
        __syncthreads();
        #pragma unroll
        for (int kk = 0; kk < 2; ++kk) {
            h8 af[2], bf[4];
            #pragma unroll
            for (int mi = 0; mi < 2; ++mi) af[mi] = *(const h8*)&As[wr + mi * 16 + lr][kk * 32 + lg * 8];
            #pragma unroll
            for (int ni = 0; ni < 4; ++ni) bf[ni] = *(const h8*)&Bs[wc + ni * 16 + lr][kk * 32 + lg * 8];
            #pragma unroll
            for (int mi = 0; mi < 2; ++mi)
                #pragma unroll
                for (int ni = 0; ni < 4; ++ni)
                    acc[mi][ni] = __builtin_amdgcn_mfma_f32_16x16x32_f16(af[mi], bf[ni], acc[mi][ni], 0, 0, 0);
        }
    }

    #pragma unroll
    for (int mi = 0; mi < 2; ++mi)
        #pragma unroll
        for (int ni = 0; ni < 4; ++ni)
            #pragma unroll
            for (int j = 0; j < 4; ++j) {
                int row = tm + wr + mi * 16 + lg * 4 + j;
                int col = tn + wc + ni * 16 + lr;
                C[(size_t)row * DMODEL + col] = acc[mi][ni][j] + bias[col];
            }
}

// ---------------- flash attention v5 ----------------
// QT=128, 8 waves (512 threads); double-buffered K/V via global_load_lds with
// pre-swizzled source (linear dest + SWZ read); 1 barrier/tile; XCD swizzle.
#define KT 64

// byte offset into a [64 rows][128B] tile with XOR swizzle
#define SWZ(row, bytecol) ((row) * 128 + ((bytecol) ^ (((row) & 7) << 4)))

__global__ __launch_bounds__(512) void flash_kernel(
    const _Float16* __restrict__ Qb,   // [4096][1024], pre-scaled by C2
    const _Float16* __restrict__ Kb,   // [4096][1024]
    const _Float16* __restrict__ Vt,   // [2][1024][2048]
    const float* __restrict__ pb,      // [2][2048] log2-domain
    _Float16* __restrict__ AO)         // [4096][1024]
{
    __shared__ __align__(16) char KsB[2][8192];        // 16KB  K tiles [k][d]
    __shared__ __align__(16) char VsB[2][8192];        // 16KB  V^T tiles [d][k]
    __shared__ __align__(16) _Float16 Ps[8][16][72];   // 18KB  per-wave P (2-way floor)

    // bijective XCD swizzle: 512 blocks = 8 XCD x 64 -> 4 heads/XCD (K/V L2-resident)
    int bid = blockIdx.x + 16 * blockIdx.y;
    int nf = (bid & 7) * 64 + (bid >> 3);
    int qx = nf & 15, bh = nf >> 4;
    int b = bh >> 4, h = bh & 15;
    int q0 = qx * 128;
    int t = threadIdx.x, wave = t >> 6, lane = t & 63;
    int lr = lane & 15, lg = lane >> 4;

    const _Float16* Khead  = Kb + (size_t)b * NSEQ * DMODEL + h * HD;
    const _Float16* Vthead = Vt + ((size_t)b * 1024 + h * HD) * NSEQ;
    const float* pbb = pb + b * NSEQ;

    // Q fragment in registers: lane holds Q row q = q0 + wave*16 + lr
    const _Float16* Qrow = Qb + ((size_t)b * NSEQ + q0 + wave * 16 + lr) * DMODEL + h * HD;
    h8 qf0 = *(const h8*)&Qrow[lg * 8];
    h8 qf1 = *(const h8*)&Qrow[32 + lg * 8];

    const h8 vones = { (_Float16)1, (_Float16)1, (_Float16)1, (_Float16)1,
                       (_Float16)1, (_Float16)1, (_Float16)1, (_Float16)1 };

    float mrun = -INFINITY;               // running max for q = lr (dup across lg)
    f32x4 oacc[4] = {};                   // O[q = lg*4+j][d = ni*16+lr]
    f32x4 lsum = {};                      // row-sum for q = lg*4+j

    // staging: 512 threads x 1 GLL per matrix; linear dest, inverse-swizzled source chunk
    int srow = t >> 3;                    // row 0..63
    int schunk = (t & 7) ^ (srow & 7);    // global 16B chunk this thread loads
    const _Float16* Ksrc = Khead + (size_t)srow * DMODEL + schunk * 8;
    const _Float16* Vsrc = Vthead + (size_t)srow * NSEQ + schunk * 8;

    // prologue: stage tile 0 into buf 0
    GLL(Ksrc, KsB[0] + wave * 1024);
    GLL(Vsrc, VsB[0] + wave * 1024);
    asm volatile("s_waitcnt vmcnt(0)" ::: "memory");
    __syncthreads();

    int cur = 0;
    for (int kt = 0; kt < 32; ++kt) {
        int k0 = kt * KT;
        // issue next-tile staging before compute (HBM latency hides under MFMA/softmax)
        if (kt < 31) {
            GLL(Ksrc + (size_t)(k0 + KT) * DMODEL, KsB[cur ^ 1] + wave * 1024);
            GLL(Vsrc + (k0 + KT), VsB[cur ^ 1] + wave * 1024);
        }
        const char* Kc = KsB[cur];
        const char* Vc = VsB[cur];

        // S^T = (C2*Q)K^T + bias : lane holds S[q=lr][k = ci*16 + lg*4 + j] (log2 domain)
        f32x4 s[4];
        #pragma unroll
        for (int ci = 0; ci < 4; ++ci)
            s[ci] = *(const f32x4*)&pbb[k0 + ci * 16 + lg * 4];
        #pragma unroll
        for (int ci = 0; ci < 4; ++ci) {
            h8 kf = *(const h8*)(Kc + SWZ(ci * 16 + lr, lg * 16));
            s[ci] = __builtin_amdgcn_mfma_f32_16x16x32_f16(kf, qf0, s[ci], 0, 0, 0);
        }
        #pragma unroll
        for (int ci = 0; ci < 4; ++ci) {
            h8 kf = *(const h8*)(Kc + SWZ(ci * 16 + lr, 64 + lg * 16));
            s[ci] = __builtin_amdgcn_mfma_f32_16x16x32_f16(kf, qf1, s[ci], 0, 0, 0);
        }

        // row max (lane-local 16 + cross-lg)
        float sm = s[0][0];
        #pragma unroll
        for (int ci = 0; ci < 4; ++ci)
            #pragma unroll
            for (int j = 0; j < 4; ++j) sm = fmaxf(sm, s[ci][j]);
        sm = fmaxf(sm, __shfl_xor(sm, 16));
        sm = fmaxf(sm, __shfl_xor(sm, 32));

        bool need = __any(sm > mrun);
        float newm = need ? fmaxf(mrun, sm) : mrun;

        // P = exp2(s - newm) -> packed f16 (cvt_pkrtz) -> per-wave LDS
        #pragma unroll
        for (int ci = 0; ci < 4; ++ci) {
            fp16x2 a = __builtin_amdgcn_cvt_pkrtz(__builtin_amdgcn_exp2f(s[ci][0] - newm),
                                                  __builtin_amdgcn_exp2f(s[ci][1] - newm));
            fp16x2 b2 = __builtin_amdgcn_cvt_pkrtz(__builtin_amdgcn_exp2f(s[ci][2] - newm),
                                                   __builtin_amdgcn_exp2f(s[ci][3] - newm));
            union { fp16x2 hh[2]; uint2 u; } pk;
            pk.hh[0] = a; pk.hh[1] = b2;
            *(uint2*)&Ps[wave][lr][ci * 16 + lg * 4] = pk.u;
        }

        // V fragments (independent of Ps)
        h8 vf[2][4];
        #pragma unroll
        for (int kb = 0; kb < 2; ++kb)
            #pragma unroll
            for (int ni = 0; ni < 4; ++ni)
                vf[kb][ni] = *(const h8*)(Vc + SWZ(ni * 16 + lr, kb * 64 + lg * 16));

        // rescale O (and sum) only when the max grew (wave-uniform branch)
        if (need) {
            float fs = __builtin_amdgcn_exp2f(mrun - newm);
            mrun = newm;
            #pragma unroll
            for (int j = 0; j < 4; ++j) {
                float fsj = __shfl(fs, (lane & 48) | (lg * 4 + j), 64);
                #pragma unroll
                for (int ni = 0; ni < 4; ++ni) oacc[ni][j] *= fsj;
                lsum[j] *= fsj;
            }
        }

        asm volatile("s_waitcnt lgkmcnt(0)" ::: "memory");
        __builtin_amdgcn_sched_barrier(0);

        // O += P @ V ; lsum += P @ 1
        #pragma unroll
        for (int kb = 0; kb < 2; ++kb) {
            h8 pa = *(const h8*)&Ps[wave][lr][kb * 32 + lg * 8];
            #pragma unroll
            for (int ni = 0; ni < 4; ++ni)
                oacc[ni] = __builtin_amdgcn_mfma_f32_16x16x32_f16(pa, vf[kb][ni], oacc[ni], 0, 0, 0);
            lsum = __builtin_amdgcn_mfma_f32_16x16x32_f16(pa, vones, lsum, 0, 0, 0);
        }

        // next tile staged & all compute-reads of buf[cur] done
        asm volatile("s_waitcnt vmcnt(0)" ::: "memory");
        __syncthreads();
        cur ^= 1;
    }

    // epilogue: divide by row-sum (already in oacc layout), write out
    #pragma unroll
    for (int j = 0; j < 4; ++j) {
        float inv = 1.0f / lsum[j];
        int row = q0 + wave * 16 + lg * 4 + j;
        #pragma unroll
        for (int ni = 0; ni < 4; ++ni)
            AO[((size_t)b * NSEQ + row) * DMODEL + h * HD + ni * 16 + lr] = (_Float16)(oacc[ni][j] * inv);
    }
}

// ---------------- launcher ----------------
extern "C" void kernel_launch(void* const* d_in, const int* in_sizes, int n_in,
                              void* d_out, int out_size, void* d_ws, size_t ws_size,
                              hipStream_t stream) {
    const float* h    = (const float*)d_in[0];
    const float* prob = (const float*)d_in[1];
    const float* Wq   = (const float*)d_in[2];
    const float* bq   = (const float*)d_in[3];
    const float* Wk   = (const float*)d_in[4];
    const float* bk   = (const float*)d_in[5];
    const float* Wv   = (const float*)d_in[6];
    const float* bv   = (const float*)d_in[7];
    const float* Wo   = (const float*)d_in[8];
    const float* bo   = (const float*)d_in[9];
    const float* pbs  = (const float*)d_in[10];

    char* ws = (char*)d_ws;
    _Float16* hpe  = (_Float16*)(ws + OFF_HPE);
    _Float16* wq16 = (_Float16*)(ws + OFF_WQ);
    _Float16* wk16 = (_Float16*)(ws + OFF_WK);
    _Float16* wv16 = (_Float16*)(ws + OFF_WV);
    _Float16* wo16 = (_Float16*)(ws + OFF_WO);
    _Float16* qb   = (_Float16*)(ws + OFF_Q);
    _Float16* kb16 = (_Float16*)(ws + OFF_K);
    _Float16* vt   = (_Float16*)(ws + OFF_VT);
    _Float16* ao   = (_Float16*)(ws + OFF_AO);
    float*    pbuf = (float*)(ws + OFF_PB);

    hpe_kernel<<<dim3(2048), dim3(256), 0, stream>>>(h, hpe);
    cast4_kernel<<<dim3(4096), dim3(256), 0, stream>>>(Wq, Wk, Wv, Wo, wq16, wk16, wv16, wo16);
    pb_kernel<<<dim3(16), dim3(256), 0, stream>>>(prob, pbs, pbuf);

    gemm_qkv<<<dim3(32, 24), dim3(256), 0, stream>>>(hpe, wq16, wk16, wv16, bq, bk, bv, qb, kb16, vt);

    flash_kernel<<<dim3(16, 32), dim3(512), 0, stream>>>(qb, kb16, vt, pbuf, ao);

    gemm_ao<<<dim3(64, 8), dim3(256), 0, stream>>>(ao, wo16, bo, (float*)d_out);
}

// Round 8
// 218.838 us; speedup vs baseline: 1.4188x; 1.0684x over previous
//
#include <hip/hip_runtime.h>

typedef _Float16 h8 __attribute__((ext_vector_type(8)));
typedef _Float16 h4 __attribute__((ext_vector_type(4)));
typedef __fp16 fp16x2 __attribute__((ext_vector_type(2)));
typedef float f32x4 __attribute__((ext_vector_type(4)));

#define NSEQ 2048
#define DMODEL 1024
#define HD 64
#define C2 0.1803368801111244f   // 0.125 * log2(e), folded into Wq/bq

// ---------------- workspace layout (bytes) ----------------
#define OFF_HPE  (size_t)0           // 4096x1024 f16 = 8MB
#define OFF_WQ   (size_t)8388608     // 1024x1024 f16 = 2MB (pre-scaled by C2)
#define OFF_WK   (size_t)10485760
#define OFF_WV   (size_t)12582912
#define OFF_WO   (size_t)14680064
#define OFF_Q    (size_t)16777216    // 4096x1024 f16 = 8MB (Q pre-scaled by C2)
#define OFF_K    (size_t)25165824
#define OFF_VT   (size_t)33554432    // [2][1024][2048] f16 = 8MB (V^T per head)
#define OFF_AO   (size_t)41943040    // 4096x1024 f16 = 8MB
#define OFF_PB   (size_t)50331648    // [2][2048] f32 (log2-domain bias)

#define GLL(g, l) __builtin_amdgcn_global_load_lds( \
    (const __attribute__((address_space(1))) unsigned int*)(const void*)(g), \
    (__attribute__((address_space(3))) unsigned int*)(l), 16, 0, 0)

// ---------------- fused prep kernel ----------------
// segment 0: h+PE -> f16 (524288 items, 8 halfs each)
// segment 1: cast 4 weight mats f32->f16 (1048576 items, 4 floats each; Wq scaled)
// segment 2: log2-domain key bias (4096 items)
__global__ void prep_kernel(const float* __restrict__ h, _Float16* __restrict__ hpe,
                            const float* __restrict__ w0, const float* __restrict__ w1,
                            const float* __restrict__ w2, const float* __restrict__ w3,
                            _Float16* __restrict__ d0, _Float16* __restrict__ d1,
                            _Float16* __restrict__ d2, _Float16* __restrict__ d3,
                            const float* __restrict__ probs, const float* __restrict__ pbs,
                            float* __restrict__ pb) {
    int idx = blockIdx.x * blockDim.x + threadIdx.x;
    if (idx < 524288) {
        int row = idx >> 7;
        int c8 = (idx & 127) * 8;
        int n = row & (NSEQ - 1);
        const float kL = -0.025952563241307517f;           // -log2(10000)/512
        const float kInv2Pi = 0.15915494309189535f;
        union { float4 f4[2]; float f[8]; } in;
        in.f4[0] = *(const float4*)&h[(size_t)row * DMODEL + c8];
        in.f4[1] = *(const float4*)&h[(size_t)row * DMODEL + c8 + 4];
        union { _Float16 hh[8]; uint4 u; } out;
        #pragma unroll
        for (int p = 0; p < 4; ++p) {
            int i2 = (c8 >> 1) + p;
            float div = __builtin_amdgcn_exp2f((float)i2 * kL);
            float rev = (float)n * div * kInv2Pi;
            float rf = __builtin_amdgcn_fractf(rev);
            float s = __builtin_amdgcn_sinf(rf);
            float c = __builtin_amdgcn_cosf(rf);
            out.hh[2 * p]     = (_Float16)(in.f[2 * p] + s);
            out.hh[2 * p + 1] = (_Float16)(in.f[2 * p + 1] + c);
        }
        *(uint4*)&hpe[(size_t)row * DMODEL + c8] = out.u;
    } else if (idx < 1572864) {
        int j = idx - 524288;
        int which = j >> 18, i2 = j & 262143;
        const float* s = which == 0 ? w0 : which == 1 ? w1 : which == 2 ? w2 : w3;
        _Float16* d    = which == 0 ? d0 : which == 1 ? d1 : which == 2 ? d2 : d3;
        float sc = which == 0 ? C2 : 1.0f;
        float4 v = ((const float4*)s)[i2];
        union { _Float16 hh[4]; uint2 u; } o;
        o.hh[0] = (_Float16)(v.x * sc); o.hh[1] = (_Float16)(v.y * sc);
        o.hh[2] = (_Float16)(v.z * sc); o.hh[3] = (_Float16)(v.w * sc);
        ((uint2*)d)[i2] = o.u;
    } else if (idx < 1576960) {
        int k = idx - 1572864;
        pb[k] = pbs[0] * log2f(probs[k] + 1e-8f);
    }
}

// ---------------- fused QKV GEMM: 256x128 tile, 8 waves, m97 staging ----------------
// grid 384 = 8 XCD x 48; byy: 0-7 -> Q (bias*C2), 8-15 -> K, 16-23 -> V^T.
__global__ __launch_bounds__(512) void gemm_qkv(
    const _Float16* __restrict__ A,
    const _Float16* __restrict__ Wqp, const _Float16* __restrict__ Wkp, const _Float16* __restrict__ Wvp,
    const float* __restrict__ bqp, const float* __restrict__ bkp, const float* __restrict__ bvp,
    _Float16* __restrict__ qb, _Float16* __restrict__ kb, _Float16* __restrict__ vt)
{
    __shared__ __align__(16) _Float16 As[256][64];   // 32KB
    __shared__ __align__(16) _Float16 Bs[128][64];   // 16KB
    // bijective XCD swizzle: 384 blocks = 8 XCD x 48
    int bid = blockIdx.x;
    int nf = (bid & 7) * 48 + (bid >> 3);
    int bx = nf & 15, byy = nf >> 4;                 // bx 0..15, byy 0..23
    int widx = byy >> 3;
    const _Float16* W = widx == 0 ? Wqp : widx == 1 ? Wkp : Wvp;
    const float* bias = widx == 0 ? bqp : widx == 1 ? bkp : bvp;
    float bscale = widx == 0 ? C2 : 1.0f;
    int tm = bx * 256;
    int tn = (byy & 7) * 128;
    int t = threadIdx.x;
    int wave = t >> 6, lane = t & 63;
    int wr = (wave >> 1) * 64, wc = (wave & 1) * 64;
    int lr = lane & 15, lg = lane >> 4;

    f32x4 acc[4][4] = {};

    int grow = lane >> 3;                // 0..7
    int gcol = (lane & 7) * 8;
    const _Float16* Aptr = A + (size_t)(tm + wave * 8 + grow) * DMODEL + gcol;
    const _Float16* Wptr = W + (size_t)(tn + wave * 8 + grow) * DMODEL + gcol;

    for (int k0 = 0; k0 < DMODEL; k0 += 64) {
        __syncthreads();
        #pragma unroll
        for (int i = 0; i < 4; ++i)
            GLL(Aptr + (size_t)i * 64 * DMODEL + k0, &As[i * 64 + wave * 8][0]);
        #pragma unroll
        for (int i = 0; i < 2; ++i)
            GLL(Wptr + (size_t)i * 64 * DMODEL + k0, &Bs[i * 64 + wave * 8][0]);
        __syncthreads();
        #pragma unroll
        for (int kk = 0; kk < 2; ++kk) {
            h8 af[4], bf[4];
            #pragma unroll
            for (int mi = 0; mi < 4; ++mi) af[mi] = *(const h8*)&As[wr + mi * 16 + lr][kk * 32 + lg * 8];
            #pragma unroll
            for (int ni = 0; ni < 4; ++ni) bf[ni] = *(const h8*)&Bs[wc + ni * 16 + lr][kk * 32 + lg * 8];
            #pragma unroll
            for (int mi = 0; mi < 4; ++mi)
                #pragma unroll
                for (int ni = 0; ni < 4; ++ni)
                    acc[mi][ni] = __builtin_amdgcn_mfma_f32_16x16x32_f16(af[mi], bf[ni], acc[mi][ni], 0, 0, 0);
        }
    }

    #pragma unroll
    for (int mi = 0; mi < 4; ++mi)
        #pragma unroll
        for (int ni = 0; ni < 4; ++ni) {
            int col = tn + wc + ni * 16 + lr;
            float bv = bias[col] * bscale;
            if (widx < 2) {
                _Float16* dst = widx == 0 ? qb : kb;
                #pragma unroll
                for (int j = 0; j < 4; ++j) {
                    int row = tm + wr + mi * 16 + lg * 4 + j;
                    dst[(size_t)row * DMODEL + col] = (_Float16)(acc[mi][ni][j] + bv);
                }
            } else {
                int row0 = tm + wr + mi * 16 + lg * 4;
                int b = row0 >> 11, n0 = row0 & 2047;
                h4 pk;
                #pragma unroll
                for (int j = 0; j < 4; ++j) pk[j] = (_Float16)(acc[mi][ni][j] + bv);
                *(h4*)&vt[((size_t)b * 1024 + col) * 2048 + n0] = pk;
            }
        }
}

// ---------------- AO GEMM: C[4096][1024] f32 = A @ Wo^T + bo ; 64x128 tile, XCD swizzle ----
__global__ __launch_bounds__(256) void gemm_ao(
    const _Float16* __restrict__ A, const _Float16* __restrict__ W,
    const float* __restrict__ bias, float* __restrict__ C)
{
    __shared__ __align__(16) _Float16 As[64][64];    // 8KB
    __shared__ __align__(16) _Float16 Bs[128][64];   // 16KB
    // bijective XCD swizzle: 512 blocks = 8 XCD x 64
    int bid = blockIdx.x + 64 * blockIdx.y;
    int nf = (bid & 7) * 64 + (bid >> 3);
    int tm = (nf & 63) * 64;
    int tn = (nf >> 6) * 128;
    int t = threadIdx.x;
    int wave = t >> 6, lane = t & 63;
    int wr = (wave >> 1) * 32, wc = (wave & 1) * 64;
    int lr = lane & 15, lg = lane >> 4;

    f32x4 acc[2][4] = {};

    int grow = lane >> 3;
    int gcol = (lane & 7) * 8;
    const _Float16* Aptr = A + (size_t)(tm + wave * 8 + grow) * DMODEL + gcol;
    const _Float16* Wptr = W + (size_t)(tn + wave * 8 + grow) * DMODEL + gcol;

    for (int k0 = 0; k0 < DMODEL; k0 += 64) {
        __syncthreads();
        #pragma unroll
        for (int i = 0; i < 2; ++i)
            GLL(Aptr + (size_t)i * 32 * DMODEL + k0, &As[i * 32 + wave * 8][0]);
        #pragma unroll
        for (int i = 0; i < 4; ++i)
            GLL(Wptr + (size_t)i * 32 * DMODEL + k0, &Bs[i * 32 + wave * 8][0]);
        __syncthreads();
        #pragma unroll
        for (int kk = 0; kk < 2; ++kk) {
            h8 af[2], bf[4];
            #pragma unroll
            for (int mi = 0; mi < 2; ++mi) af[mi] = *(const h8*)&As[wr + mi * 16 + lr][kk * 32 + lg * 8];
            #pragma unroll
            for (int ni = 0; ni < 4; ++ni) bf[ni] = *(const h8*)&Bs[wc + ni * 16 + lr][kk * 32 + lg * 8];
            #pragma unroll
            for (int mi = 0; mi < 2; ++mi)
                #pragma unroll
                for (int ni = 0; ni < 4; ++ni)
                    acc[mi][ni] = __builtin_amdgcn_mfma_f32_16x16x32_f16(af[mi], bf[ni], acc[mi][ni], 0, 0, 0);
        }
    }

    #pragma unroll
    for (int mi = 0; mi < 2; ++mi)
        #pragma unroll
        for (int ni = 0; ni < 4; ++ni)
            #pragma unroll
            for (int j = 0; j < 4; ++j) {
                int row = tm + wr + mi * 16 + lg * 4 + j;
                int col = tn + wc + ni * 16 + lr;
                C[(size_t)row * DMODEL + col] = acc[mi][ni][j] + bias[col];
            }
}

// ---------------- flash attention v6 ----------------
// Early barrier: all LDS reads (QK frags + V frags) before vmcnt(0)+barrier;
// softmax/Ps/PV are post-barrier register work -> waves de-lockstep.
#define KT 64

// byte offset into a [64 rows][128B] tile with XOR swizzle
#define SWZ(row, bytecol) ((row) * 128 + ((bytecol) ^ (((row) & 7) << 4)))

__global__ __launch_bounds__(512) void flash_kernel(
    const _Float16* __restrict__ Qb,   // [4096][1024], pre-scaled by C2
    const _Float16* __restrict__ Kb,   // [4096][1024]
    const _Float16* __restrict__ Vt,   // [2][1024][2048]
    const float* __restrict__ pb,      // [2][2048] log2-domain
    _Float16* __restrict__ AO)         // [4096][1024]
{
    __shared__ __align__(16) char KsB[2][8192];        // 16KB  K tiles [k][d]
    __shared__ __align__(16) char VsB[2][8192];        // 16KB  V^T tiles [d][k]
    __shared__ __align__(16) _Float16 Ps[8][16][72];   // 18KB  per-wave P (2-way floor)

    // bijective XCD swizzle: 512 blocks = 8 XCD x 64 -> 4 heads/XCD (K/V L2-resident)
    int bid = blockIdx.x + 16 * blockIdx.y;
    int nf = (bid & 7) * 64 + (bid >> 3);
    int qx = nf & 15, bh = nf >> 4;
    int b = bh >> 4, h = bh & 15;
    int q0 = qx * 128;
    int t = threadIdx.x, wave = t >> 6, lane = t & 63;
    int lr = lane & 15, lg = lane >> 4;

    const _Float16* Khead  = Kb + (size_t)b * NSEQ * DMODEL + h * HD;
    const _Float16* Vthead = Vt + ((size_t)b * 1024 + h * HD) * NSEQ;
    const float* pbb = pb + b * NSEQ;

    // Q fragment in registers: lane holds Q row q = q0 + wave*16 + lr
    const _Float16* Qrow = Qb + ((size_t)b * NSEQ + q0 + wave * 16 + lr) * DMODEL + h * HD;
    h8 qf0 = *(const h8*)&Qrow[lg * 8];
    h8 qf1 = *(const h8*)&Qrow[32 + lg * 8];

    const h8 vones = { (_Float16)1, (_Float16)1, (_Float16)1, (_Float16)1,
                       (_Float16)1, (_Float16)1, (_Float16)1, (_Float16)1 };

    float mrun = -INFINITY;               // running max for q = lr (dup across lg)
    f32x4 oacc[4] = {};                   // O[q = lg*4+j][d = ni*16+lr]
    f32x4 lsum = {};                      // row-sum for q = lg*4+j

    // staging: 512 threads x 1 GLL per matrix; linear dest, inverse-swizzled source chunk
    int srow = t >> 3;                    // row 0..63
    int schunk = (t & 7) ^ (srow & 7);    // global 16B chunk this thread loads
    const _Float16* Ksrc = Khead + (size_t)srow * DMODEL + schunk * 8;
    const _Float16* Vsrc = Vthead + (size_t)srow * NSEQ + schunk * 8;

    // prologue: stage tile 0 into buf 0
    GLL(Ksrc, KsB[0] + wave * 1024);
    GLL(Vsrc, VsB[0] + wave * 1024);
    asm volatile("s_waitcnt vmcnt(0)" ::: "memory");
    __syncthreads();

    int cur = 0;
    for (int kt = 0; kt < 32; ++kt) {
        int k0 = kt * KT;
        // issue next-tile staging (completes under this tile's LDS-read phase)
        if (kt < 31) {
            GLL(Ksrc + (size_t)(k0 + KT) * DMODEL, KsB[cur ^ 1] + wave * 1024);
            GLL(Vsrc + (k0 + KT), VsB[cur ^ 1] + wave * 1024);
        }
        const char* Kc = KsB[cur];
        const char* Vc = VsB[cur];

        // S^T = (C2*Q)K^T + bias : lane holds S[q=lr][k = ci*16 + lg*4 + j] (log2 domain)
        f32x4 s[4];
        #pragma unroll
        for (int ci = 0; ci < 4; ++ci)
            s[ci] = *(const f32x4*)&pbb[k0 + ci * 16 + lg * 4];
        __builtin_amdgcn_s_setprio(1);
        #pragma unroll
        for (int ci = 0; ci < 4; ++ci) {
            h8 kf = *(const h8*)(Kc + SWZ(ci * 16 + lr, lg * 16));
            s[ci] = __builtin_amdgcn_mfma_f32_16x16x32_f16(kf, qf0, s[ci], 0, 0, 0);
        }
        #pragma unroll
        for (int ci = 0; ci < 4; ++ci) {
            h8 kf = *(const h8*)(Kc + SWZ(ci * 16 + lr, 64 + lg * 16));
            s[ci] = __builtin_amdgcn_mfma_f32_16x16x32_f16(kf, qf1, s[ci], 0, 0, 0);
        }
        __builtin_amdgcn_s_setprio(0);

        // V fragments -> registers (last LDS reads of buf[cur])
        h8 vf[2][4];
        #pragma unroll
        for (int kb = 0; kb < 2; ++kb)
            #pragma unroll
            for (int ni = 0; ni < 4; ++ni)
                vf[kb][ni] = *(const h8*)(Vc + SWZ(ni * 16 + lr, kb * 64 + lg * 16));

        // EARLY barrier: buf[cur] fully consumed; next tile staged. Post-barrier work
        // is register-only, so waves de-lockstep and overlap across tiles.
        asm volatile("s_waitcnt vmcnt(0) lgkmcnt(0)" ::: "memory");
        __syncthreads();
        cur ^= 1;

        // row max (lane-local 16 + cross-lg)
        float sm = s[0][0];
        #pragma unroll
        for (int ci = 0; ci < 4; ++ci)
            #pragma unroll
            for (int j = 0; j < 4; ++j) sm = fmaxf(sm, s[ci][j]);
        sm = fmaxf(sm, __shfl_xor(sm, 16));
        sm = fmaxf(sm, __shfl_xor(sm, 32));

        bool need = __any(sm > mrun);
        float newm = need ? fmaxf(mrun, sm) : mrun;

        // P = exp2(s - newm) -> packed f16 (cvt_pkrtz) -> per-wave LDS
        #pragma unroll
        for (int ci = 0; ci < 4; ++ci) {
            fp16x2 a = __builtin_amdgcn_cvt_pkrtz(__builtin_amdgcn_exp2f(s[ci][0] - newm),
                                                  __builtin_amdgcn_exp2f(s[ci][1] - newm));
            fp16x2 b2 = __builtin_amdgcn_cvt_pkrtz(__builtin_amdgcn_exp2f(s[ci][2] - newm),
                                                   __builtin_amdgcn_exp2f(s[ci][3] - newm));
            union { fp16x2 hh[2]; uint2 u; } pk;
            pk.hh[0] = a; pk.hh[1] = b2;
            *(uint2*)&Ps[wave][lr][ci * 16 + lg * 4] = pk.u;
        }

        // rescale O (and sum) only when the max grew (wave-uniform branch)
        if (need) {
            float fs = __builtin_amdgcn_exp2f(mrun - newm);
            mrun = newm;
            #pragma unroll
            for (int j = 0; j < 4; ++j) {
                float fsj = __shfl(fs, (lane & 48) | (lg * 4 + j), 64);
                #pragma unroll
                for (int ni = 0; ni < 4; ++ni) oacc[ni][j] *= fsj;
                lsum[j] *= fsj;
            }
        }

        asm volatile("s_waitcnt lgkmcnt(0)" ::: "memory");
        __builtin_amdgcn_sched_barrier(0);

        // O += P @ V ; lsum += P @ 1
        __builtin_amdgcn_s_setprio(1);
        #pragma unroll
        for (int kb = 0; kb < 2; ++kb) {
            h8 pa = *(const h8*)&Ps[wave][lr][kb * 32 + lg * 8];
            #pragma unroll
            for (int ni = 0; ni < 4; ++ni)
                oacc[ni] = __builtin_amdgcn_mfma_f32_16x16x32_f16(pa, vf[kb][ni], oacc[ni], 0, 0, 0);
            lsum = __builtin_amdgcn_mfma_f32_16x16x32_f16(pa, vones, lsum, 0, 0, 0);
        }
        __builtin_amdgcn_s_setprio(0);
    }

    // epilogue: divide by row-sum (already in oacc layout), write out
    #pragma unroll
    for (int j = 0; j < 4; ++j) {
        float inv = 1.0f / lsum[j];
        int row = q0 + wave * 16 + lg * 4 + j;
        #pragma unroll
        for (int ni = 0; ni < 4; ++ni)
            AO[((size_t)b * NSEQ + row) * DMODEL + h * HD + ni * 16 + lr] = (_Float16)(oacc[ni][j] * inv);
    }
}

// ---------------- launcher ----------------
extern "C" void kernel_launch(void* const* d_in, const int* in_sizes, int n_in,
                              void* d_out, int out_size, void* d_ws, size_t ws_size,
                              hipStream_t stream) {
    const float* h    = (const float*)d_in[0];
    const float* prob = (const float*)d_in[1];
    const float* Wq   = (const float*)d_in[2];
    const float* bq   = (const float*)d_in[3];
    const float* Wk   = (const float*)d_in[4];
    const float* bk   = (const float*)d_in[5];
    const float* Wv   = (const float*)d_in[6];
    const float* bv   = (const float*)d_in[7];
    const float* Wo   = (const float*)d_in[8];
    const float* bo   = (const float*)d_in[9];
    const float* pbs  = (const float*)d_in[10];

    char* ws = (char*)d_ws;
    _Float16* hpe  = (_Float16*)(ws + OFF_HPE);
    _Float16* wq16 = (_Float16*)(ws + OFF_WQ);
    _Float16* wk16 = (_Float16*)(ws + OFF_WK);
    _Float16* wv16 = (_Float16*)(ws + OFF_WV);
    _Float16* wo16 = (_Float16*)(ws + OFF_WO);
    _Float16* qb   = (_Float16*)(ws + OFF_Q);
    _Float16* kb16 = (_Float16*)(ws + OFF_K);
    _Float16* vt   = (_Float16*)(ws + OFF_VT);
    _Float16* ao   = (_Float16*)(ws + OFF_AO);
    float*    pbuf = (float*)(ws + OFF_PB);

    prep_kernel<<<dim3(6160), dim3(256), 0, stream>>>(
        h, hpe, Wq, Wk, Wv, Wo, wq16, wk16, wv16, wo16, prob, pbs, pbuf);

    gemm_qkv<<<dim3(384), dim3(512), 0, stream>>>(hpe, wq16, wk16, wv16, bq, bk, bv, qb, kb16, vt);

    flash_kernel<<<dim3(16, 32), dim3(512), 0, stream>>>(qb, kb16, vt, pbuf, ao);

    gemm_ao<<<dim3(64, 8), dim3(256), 0, stream>>>(ao, wo16, bo, (float*)d_out);
}